// Round 2
// baseline (4840.818 us; speedup 1.0000x reference)
//
#include <hip/hip_runtime.h>
#include <cstdint>

// Problem constants
constexpr int N = 8192, E = 262144, D = 128, O = 64, C = 4096;

#define DEV __device__ __forceinline__

// orderable-uint mapping for float atomicMin/Max and packed argmax
DEV unsigned fmap(float f) {
  unsigned u = __float_as_uint(f);
  return (u & 0x80000000u) ? ~u : (u | 0x80000000u);
}
DEV float funmap(unsigned u) {
  unsigned b = (u & 0x80000000u) ? (u & 0x7FFFFFFFu) : ~u;
  return __uint_as_float(b);
}

// ---------------- setup kernels ----------------

__global__ __launch_bounds__(256) void k_init(uint32_t* scal_u) {
  if (threadIdx.x == 0 && blockIdx.x == 0) scal_u[0] = 0xFFFFFFFFu;  // min slot
}

// degrees + adjacency bitmask + unique-edge count
__global__ __launch_bounds__(256) void k_degree(const int* __restrict__ src, const int* __restrict__ dst,
    uint32_t* __restrict__ bits, int* __restrict__ dego, int* __restrict__ degi,
    uint32_t* __restrict__ scal_u) {
  int e = blockIdx.x * 256 + threadIdx.x;
  int s = src[e], d = dst[e];
  atomicAdd(&dego[s], 1);
  atomicAdd(&degi[d], 1);
  unsigned idx = (unsigned)s * 8192u + (unsigned)d;
  unsigned bit = 1u << (idx & 31);
  unsigned old = atomicOr(&bits[idx >> 5], bit);
  bool isnew = !(old & bit);
  unsigned long long b = __ballot(isnew);
  if ((threadIdx.x & 63) == 0) atomicAdd(&scal_u[2], (unsigned)__popcll(b));
}

__global__ __launch_bounds__(256) void k_norms(const int* __restrict__ dego, const int* __restrict__ degi,
                                               float* __restrict__ nsrc, float* __restrict__ ndst) {
  int i = blockIdx.x * 256 + threadIdx.x;
  if (i >= N) return;
  int a = dego[i], b = degi[i];
  nsrc[i] = a > 0 ? 1.0f / sqrtf((float)a) : 0.0f;
  ndst[i] = b > 0 ? 1.0f / sqrtf((float)b) : 0.0f;
}

// exclusive scan of deg_in -> row_ptr, cursor (single block, 1024 threads, 8 elems each)
__global__ __launch_bounds__(1024) void k_scan(const int* __restrict__ degi, int* __restrict__ rowptr,
                                               int* __restrict__ cursor) {
  __shared__ int sh[1024];
  int tid = threadIdx.x;
  int base = tid * 8;
  int v[8];
  int s = 0;
#pragma unroll
  for (int j = 0; j < 8; ++j) { v[j] = degi[base + j]; s += v[j]; }
  sh[tid] = s;
  __syncthreads();
  for (int off = 1; off < 1024; off <<= 1) {
    int t = (tid >= off) ? sh[tid - off] : 0;
    __syncthreads();
    sh[tid] += t;
    __syncthreads();
  }
  int run = (tid == 0) ? 0 : sh[tid - 1];
#pragma unroll
  for (int j = 0; j < 8; ++j) { rowptr[base + j] = run; cursor[base + j] = run; run += v[j]; }
  if (tid == 1023) rowptr[N] = run;
}

__global__ __launch_bounds__(256) void k_scatter(const int* __restrict__ src, const int* __restrict__ dst,
                                                 int* __restrict__ cursor, int* __restrict__ csr) {
  int e = blockIdx.x * 256 + threadIdx.x;
  int d = dst[e];
  int pos = atomicAdd(&cursor[d], 1);
  csr[pos] = src[e];
}

// out[i,:] = in[i,:] * norm[i]  (float4 over N*32)
__global__ __launch_bounds__(256) void k_scale(const float4* __restrict__ in, const float* __restrict__ norm,
                                               float4* __restrict__ out) {
  int i = blockIdx.x * 256 + threadIdx.x;
  if (i >= N * 32) return;
  float s = norm[i >> 5];
  float4 v = in[i];
  v.x *= s; v.y *= s; v.z *= s; v.w *= s;
  out[i] = v;
}

// CSR gather-aggregate: out[row,:] = (sum over in-edges of tmp[src,:]) * ndst[row]
__global__ __launch_bounds__(128) void k_aggregate(const int* __restrict__ rowptr, const int* __restrict__ csr,
    const float* __restrict__ tmp, const float* __restrict__ ndst, float* __restrict__ out) {
  int row = blockIdx.x, t = threadIdx.x;
  int e0 = rowptr[row], e1 = rowptr[row + 1];
  float acc = 0.f;
  int e = e0;
  for (; e + 4 <= e1; e += 4) {
    int s0 = csr[e], s1 = csr[e + 1], s2 = csr[e + 2], s3 = csr[e + 3];
    acc += tmp[s0 * 128 + t];
    acc += tmp[s1 * 128 + t];
    acc += tmp[s2 * 128 + t];
    acc += tmp[s3 * 128 + t];
  }
  for (; e < e1; ++e) acc += tmp[csr[e] * 128 + t];
  out[row * 128 + t] = acc * ndst[row];
}

// row-wise l2 normalize (one wave per row). out_extra: optional scalar-store copy (misaligned base ok)
__global__ __launch_bounds__(256) void k_l2norm(const float* __restrict__ in, float* __restrict__ out_al,
                                                float* __restrict__ out_extra, int rows) {
  int wave = threadIdx.x >> 6, lane = threadIdx.x & 63;
  int row = blockIdx.x * 4 + wave;
  if (row >= rows) return;
  float2 v = ((const float2*)in)[row * 64 + lane];
  float ss = v.x * v.x + v.y * v.y;
#pragma unroll
  for (int o = 32; o > 0; o >>= 1) ss += __shfl_xor(ss, o);
  float den = fmaxf(sqrtf(ss), 1e-12f);
  float ox = v.x / den, oy = v.y / den;
  ((float2*)out_al)[row * 64 + lane] = make_float2(ox, oy);
  if (out_extra != nullptr) {
    out_extra[row * 128 + 2 * lane] = ox;
    out_extra[row * 128 + 2 * lane + 1] = oy;
  }
}

// ---------------- small matmul: out[M,CO] = A[M,128] @ W[128,CO] + bias (+relu) ----------------
template <int CO, bool RELU>
__global__ __launch_bounds__(256, 2) void k_mm(const float* __restrict__ A, const float* __restrict__ W,
    const float* __restrict__ bias, float* __restrict__ out) {
  constexpr int CG = CO / 4;       // col f4 groups
  constexpr int RG = 256 / CG;     // row groups
  constexpr int TR = RG * 4;       // tile rows (CO=128 -> 32, CO=64 -> 64)
  constexpr int WIT = (64 * CG) / 256;
  __shared__ __align__(16) float Al[TR * 128];
  __shared__ __align__(16) float Wl[64 * CO];
  int tid = threadIdx.x;
  int cg = tid % CG, rg = tid / CG;
  int rbase = blockIdx.x * TR;
#pragma unroll
  for (int it = 0; it < TR / 8; ++it) {
    int idx = tid + it * 256;
    int r = idx >> 5, c = idx & 31;
    *(float4*)&Al[r * 128 + c * 4] = *(const float4*)&A[(rbase + r) * 128 + c * 4];
  }
  float acc[4][4] = {};
  for (int kc = 0; kc < 128; kc += 64) {
    __syncthreads();
#pragma unroll
    for (int it = 0; it < WIT; ++it) {
      int idx = tid + it * 256;
      int r = idx / CG, c = idx % CG;
      *(float4*)&Wl[r * CO + c * 4] = *(const float4*)&W[(kc + r) * CO + c * 4];
    }
    __syncthreads();
#pragma unroll
    for (int k = 0; k < 64; ++k) {
      float4 w4 = *(const float4*)&Wl[k * CO + cg * 4];
#pragma unroll
      for (int i = 0; i < 4; ++i) {
        float a = Al[(rg * 4 + i) * 128 + kc + k];
        acc[i][0] += a * w4.x; acc[i][1] += a * w4.y; acc[i][2] += a * w4.z; acc[i][3] += a * w4.w;
      }
    }
  }
  float4 b4 = *(const float4*)&bias[cg * 4];
#pragma unroll
  for (int i = 0; i < 4; ++i) {
    float4 o;
    o.x = acc[i][0] + b4.x; o.y = acc[i][1] + b4.y; o.z = acc[i][2] + b4.z; o.w = acc[i][3] + b4.w;
    if (RELU) { o.x = fmaxf(o.x, 0.f); o.y = fmaxf(o.y, 0.f); o.z = fmaxf(o.z, 0.f); o.w = fmaxf(o.w, 0.f); }
    *(float4*)&out[(rbase + rg * 4 + i) * CO + cg * 4] = o;
  }
}

// ---------------- big NT GEMM: C = A @ B^T, 128x128 tile, 8x8 micro-tile ----------------
// ADJQ=false: writes dist + fused row argmax.  ADJQ=true: upper-triangle blocks only,
// fused sum/sumsq/min/max/edge-masked sum (adj never materialized).
template <bool ADJQ>
__global__ __launch_bounds__(256, 2) void k_gemm(const float* __restrict__ A, const float* __restrict__ B,
    float* __restrict__ dout, unsigned long long* __restrict__ amax, const uint32_t* __restrict__ bits,
    double* __restrict__ scal_d, uint32_t* __restrict__ scal_u) {
  int bx = blockIdx.x, by = blockIdx.y;
  if (ADJQ && bx < by) return;   // symmetry: only col-tile >= row-tile
  int rbase = by * 128, cbase = bx * 128;
  __shared__ __align__(16) float Al[128 * 64];
  __shared__ __align__(16) float Bl[128 * 64];
  int tid = threadIdx.x;
  int tx = tid & 15, ty = tid >> 4;
  float acc[8][8];
#pragma unroll
  for (int i = 0; i < 8; ++i)
#pragma unroll
    for (int j = 0; j < 8; ++j) acc[i][j] = 0.f;

  for (int kc = 0; kc < 128; kc += 64) {
#pragma unroll
    for (int it = 0; it < 8; ++it) {
      int idx = tid + it * 256;
      int r = idx >> 4, c = idx & 15;
      // XOR swizzle: slot4 = c ^ (r&15) -> conflict-free b128 reads in the inner loop
      float4 av = *(const float4*)&A[(rbase + r) * 128 + kc + c * 4];
      *(float4*)&Al[r * 64 + ((c ^ (r & 15)) << 2)] = av;
      float4 bv = *(const float4*)&B[(cbase + r) * 128 + kc + c * 4];
      *(float4*)&Bl[r * 64 + ((c ^ (r & 15)) << 2)] = bv;
    }
    __syncthreads();
#pragma unroll
    for (int k4 = 0; k4 < 16; ++k4) {
      float4 a[8], b[8];
      int sa = ((k4 ^ ty) << 2);
      int sb = ((k4 ^ tx) << 2);
#pragma unroll
      for (int i = 0; i < 8; ++i) a[i] = *(const float4*)&Al[(ty + (i << 4)) * 64 + sa];
#pragma unroll
      for (int j = 0; j < 8; ++j) b[j] = *(const float4*)&Bl[(tx + (j << 4)) * 64 + sb];
#pragma unroll
      for (int i = 0; i < 8; ++i)
#pragma unroll
        for (int j = 0; j < 8; ++j)
          acc[i][j] += a[i].x * b[j].x + a[i].y * b[j].y + a[i].z * b[j].z + a[i].w * b[j].w;
    }
    __syncthreads();
  }

  if (!ADJQ) {
    float bestv[8];
    int bestc[8];
#pragma unroll
    for (int i = 0; i < 8; ++i) { bestv[i] = -3.4e38f; bestc[i] = 0; }
#pragma unroll
    for (int i = 0; i < 8; ++i) {
      int row = rbase + ty + (i << 4);
#pragma unroll
      for (int j = 0; j < 8; ++j) {
        int col = cbase + tx + (j << 4);
        float v = acc[i][j];
        dout[row * 4096 + col] = v;   // scalar store: dist base is float-misaligned for float4
        if (v > bestv[i]) { bestv[i] = v; bestc[i] = col; }  // strict > keeps lowest col (np tie rule)
      }
    }
    unsigned long long* sc = (unsigned long long*)Al;  // reuse (safe: past last barrier, Al unread)
#pragma unroll
    for (int i = 0; i < 8; ++i)
      sc[(ty + (i << 4)) * 16 + tx] =
          (((unsigned long long)fmap(bestv[i])) << 32) | (unsigned long long)(0xFFFFFFFFu - (unsigned)bestc[i]);
    __syncthreads();
    if (tid < 128) {
      unsigned long long m = 0ull;
#pragma unroll
      for (int k = 0; k < 16; ++k) {
        unsigned long long t = sc[tid * 16 + k];
        m = t > m ? t : m;
      }
      atomicMax(&amax[rbase + tid], m);
    }
  } else {
    // stage adjacency bit tile (both orientations) into LDS
    uint32_t* bl = (uint32_t*)Al;   // bl[lr*4 + w]  : bits for (rbase+lr, cbase..cbase+127)
    uint32_t* blT = bl + 512;       // blT[lc*4 + w] : bits for (cbase+lc, rbase..rbase+127)
#pragma unroll
    for (int it = 0; it < 2; ++it) {
      int idx = tid + it * 256;  // 0..511
      int r = idx >> 2, wq = idx & 3;
      bl[idx] = bits[(rbase + r) * 256 + (cbase >> 5) + wq];
      blT[idx] = bits[(cbase + r) * 256 + (rbase >> 5) + wq];
    }
    __syncthreads();
    double lsum = 0.0, lsq = 0.0, les = 0.0;
    float lmin = 3.4e38f, lmax = -3.4e38f;
    bool diag = (bx == by);
#pragma unroll
    for (int i = 0; i < 8; ++i) {
      int lr = ty + (i << 4);
      int row = rbase + lr;
#pragma unroll
      for (int j = 0; j < 8; ++j) {
        int lc = tx + (j << 4);
        int col = cbase + lc;
        if (diag && col < row) continue;   // only upper triangle (incl. diagonal)
        float v = acc[i][j];
        double dv = (double)v;
        double wgt = (col == row) ? 1.0 : 2.0;
        lsum += wgt * dv;
        lsq += wgt * dv * dv;
        lmin = fminf(lmin, v);
        lmax = fmaxf(lmax, v);
        unsigned eb = (bl[lr * 4 + (lc >> 5)] >> (lc & 31)) & 1u;
        if (col != row) eb += (blT[lc * 4 + (lr >> 5)] >> (lr & 31)) & 1u;
        if (eb) les += (double)eb * dv;
      }
    }
#pragma unroll
    for (int o = 32; o > 0; o >>= 1) {
      lsum += __shfl_xor(lsum, o);
      lsq += __shfl_xor(lsq, o);
      les += __shfl_xor(les, o);
      lmin = fminf(lmin, __shfl_xor(lmin, o));
      lmax = fmaxf(lmax, __shfl_xor(lmax, o));
    }
    if ((tid & 63) == 0) {
      atomicAdd(&scal_d[0], lsum);
      atomicAdd(&scal_d[1], lsq);
      atomicAdd(&scal_d[2], les);
      atomicMin(&scal_u[0], fmap(lmin));
      atomicMax(&scal_u[1], fmap(lmax));
    }
  }
}

// gather chosen codes -> quantized output; accumulate commit loss sum
__global__ __launch_bounds__(128) void k_q(const unsigned long long* __restrict__ amax,
    const float* __restrict__ cnws, const float* __restrict__ h1, float* __restrict__ qout,
    double* __restrict__ scal_d) {
  int row = blockIdx.x, t = threadIdx.x;
  unsigned long long key = amax[row];
  int col = (int)(0xFFFFFFFFu - (uint32_t)(key & 0xFFFFFFFFull));
  float q = cnws[col * 128 + t];
  qout[row * 128 + t] = q;
  float dd = q - h1[row * 128 + t];
  float ss = dd * dd;
#pragma unroll
  for (int o = 32; o > 0; o >>= 1) ss += __shfl_xor(ss, o);
  __shared__ float p[2];
  if ((t & 63) == 0) p[t >> 6] = ss;
  __syncthreads();
  if (t == 0) atomicAdd(&scal_d[3], (double)(p[0] + p[1]));
}

// sum of squared diff (h1 - quantized_node) -> scal_d[4]
__global__ __launch_bounds__(256) void k_sqdiff(const float4* __restrict__ a, const float4* __restrict__ b,
                                                double* __restrict__ scal_d) {
  int i = blockIdx.x * 256 + threadIdx.x;
  float s = 0.f;
  const int total = N * 32;
  for (; i < total; i += gridDim.x * 256) {
    float4 x = a[i], y = b[i];
    float d0 = x.x - y.x, d1 = x.y - y.y, d2 = x.z - y.z, d3 = x.w - y.w;
    s += d0 * d0 + d1 * d1 + d2 * d2 + d3 * d3;
  }
#pragma unroll
  for (int o = 32; o > 0; o >>= 1) s += __shfl_xor(s, o);
  if ((threadIdx.x & 63) == 0) atomicAdd(&scal_d[4], (double)s);
}

// final scalar combination
__global__ void k_loss(const double* __restrict__ scal_d, const uint32_t* __restrict__ scal_u,
                       float* __restrict__ o_loss) {
  if (threadIdx.x != 0 || blockIdx.x != 0) return;
  double sum = scal_d[0], sq = scal_d[1], es = scal_d[2];
  double mn = (double)funmap(scal_u[0]);
  double mx = (double)funmap(scal_u[1]);
  double U = (double)scal_u[2];
  const double N2 = 67108864.0;  // 8192^2
  double s = 1.0 / (mx - mn);
  // sum over all (i,j) of (adj - (aq-mn)*s)^2, with adj=1 on U unique edge slots
  double mean = (s * s * (sq - 2.0 * mn * sum + mn * mn * N2) - 2.0 * s * (es - mn * U) + U) / N2;
  double edge = sqrt(mean);
  double commit = 0.25 * scal_d[3] / 1048576.0;
  double frec = scal_d[4] / 1048576.0;
  *o_loss = (float)(frec + edge + commit);
}

extern "C" void kernel_launch(void* const* d_in, const int* in_sizes, int n_in,
                              void* d_out, int out_size, void* d_ws, size_t ws_size,
                              hipStream_t stream) {
  (void)in_sizes; (void)n_in; (void)out_size;
  const float* feats = (const float*)d_in[0];
  const int* src = (const int*)d_in[1];
  const int* dst = (const int*)d_in[2];
  const float* W1 = (const float*)d_in[3];
  const float* b1 = (const float*)d_in[4];
  const float* W2 = (const float*)d_in[5];
  const float* b2 = (const float*)d_in[6];
  const float* dec1W = (const float*)d_in[7];
  const float* dec1b = (const float*)d_in[8];
  const float* dec2W = (const float*)d_in[9];
  const float* dec2b = (const float*)d_in[10];
  const float* linW = (const float*)d_in[11];
  const float* linb = (const float*)d_in[12];
  const float* codebook = (const float*)d_in[13];

  float* out = (float*)d_out;
  float* o_h1 = out;                    // [N,128]
  float* o_q = out + 1048576;           // [N,128]
  float* o_h3 = out + 2097152;          // [N,128]
  float* o_out = out + 3145728;         // [N,64]
  float* o_loss = out + 3670016;        // scalar
  float* o_dist = out + 3670017;        // [N,4096] (float-misaligned base!)
  float* o_cn = out + 37224449;         // [C,128]  (float-misaligned base!)

  char* w = (char*)d_ws;
  size_t off = 0;
  auto alloc = [&](size_t b) { char* p = w + off; off = (off + b + 255) & ~(size_t)255; return p; };
  uint32_t* bits = (uint32_t*)alloc(8388608);            // N*N/8 adjacency bitmask
  int* dego = (int*)alloc(N * 4);
  int* degi = (int*)alloc(N * 4);
  unsigned long long* amax = (unsigned long long*)alloc(N * 8);
  double* scal_d = (double*)alloc(256);                  // [0]=sum [1]=sumsq [2]=edge-sum [3]=commit [4]=frec
  uint32_t* scal_u = (uint32_t*)(scal_d + 8);            // [0]=min [1]=max [2]=U
  size_t zero_bytes = off;                               // everything above must start at 0
  int* rowptr = (int*)alloc((N + 1) * 4);
  int* cursor = (int*)alloc(N * 4);
  int* csr = (int*)alloc(E * 4);
  float* nsrc = (float*)alloc(N * 4);
  float* ndst = (float*)alloc(N * 4);
  float* tmp = (float*)alloc((size_t)N * D * 4);
  float* agg = (float*)alloc((size_t)N * D * 4);
  float* xn = (float*)alloc((size_t)N * D * 4);
  float* cnws = (float*)alloc((size_t)C * D * 4);        // aligned copy of cn
  float* qe = (float*)alloc((size_t)N * D * 4);
  float* qn = (float*)alloc((size_t)N * D * 4);
  if (ws_size < off) return;  // insufficient scratch (will fail validation loudly)

  hipMemsetAsync(d_ws, 0, zero_bytes, stream);
  k_init<<<1, 256, 0, stream>>>(scal_u);

  // graph structure
  k_degree<<<E / 256, 256, 0, stream>>>(src, dst, bits, dego, degi, scal_u);
  k_norms<<<N / 256, 256, 0, stream>>>(dego, degi, nsrc, ndst);
  k_scan<<<1, 1024, 0, stream>>>(degi, rowptr, cursor);
  k_scatter<<<E / 256, 256, 0, stream>>>(src, dst, cursor, csr);

  // conv1: h1 = relu((scatter(feats*nsrc)*ndst) @ W1 + b1)
  k_scale<<<N * 32 / 256, 256, 0, stream>>>((const float4*)feats, nsrc, (float4*)tmp);
  k_aggregate<<<N, 128, 0, stream>>>(rowptr, csr, tmp, ndst, agg);
  k_mm<128, true><<<N / 32, 256, 0, stream>>>(agg, W1, b1, o_h1);

  // VQ: cn, xn, dist (+argmax), q, commit loss
  k_l2norm<<<C / 4, 256, 0, stream>>>(codebook, cnws, o_cn, C);
  k_l2norm<<<N / 4, 256, 0, stream>>>(o_h1, xn, nullptr, N);
  k_gemm<false><<<dim3(C / 128, N / 128), 256, 0, stream>>>(xn, cnws, o_dist, amax, nullptr, nullptr, nullptr);
  k_q<<<N, 128, 0, stream>>>(amax, cnws, o_h1, o_q, scal_d);

  // decoders
  k_mm<128, false><<<N / 32, 256, 0, stream>>>(o_q, dec1W, dec1b, qe);
  k_mm<128, false><<<N / 32, 256, 0, stream>>>(o_q, dec2W, dec2b, qn);
  k_sqdiff<<<512, 256, 0, stream>>>((const float4*)o_h1, (const float4*)qn, scal_d);

  // adjacency reconstruction loss (fused reductions, upper-triangle only)
  k_gemm<true><<<dim3(N / 128, N / 128), 256, 0, stream>>>(qe, qe, nullptr, nullptr, bits, scal_d, scal_u);

  // conv2 on quantized_edge + linear head
  k_scale<<<N * 32 / 256, 256, 0, stream>>>((const float4*)qe, nsrc, (float4*)tmp);
  k_aggregate<<<N, 128, 0, stream>>>(rowptr, csr, tmp, ndst, agg);
  k_mm<128, true><<<N / 32, 256, 0, stream>>>(agg, W2, b2, o_h3);
  k_mm<64, false><<<N / 64, 256, 0, stream>>>(o_h3, linW, linb, o_out);

  k_loss<<<1, 64, 0, stream>>>(scal_d, scal_u, o_loss);
}

// Round 3
// 3175.580 us; speedup vs baseline: 1.5244x; 1.5244x over previous
//
#include <hip/hip_runtime.h>
#include <cstdint>

// Problem constants
constexpr int N = 8192, E = 262144, D = 128, O = 64, C = 4096;

#define DEV __device__ __forceinline__

// orderable-uint mapping for float atomicMin/Max and packed argmax
DEV unsigned fmap(float f) {
  unsigned u = __float_as_uint(f);
  return (u & 0x80000000u) ? ~u : (u | 0x80000000u);
}
DEV float funmap(unsigned u) {
  unsigned b = (u & 0x80000000u) ? (u & 0x7FFFFFFFu) : ~u;
  return __uint_as_float(b);
}

// ---------------- setup kernels ----------------

__global__ __launch_bounds__(256) void k_init(uint32_t* scal_u) {
  if (threadIdx.x == 0 && blockIdx.x == 0) scal_u[0] = 0xFFFFFFFFu;  // min slot
}

// degrees + adjacency bitmask + unique-edge count
__global__ __launch_bounds__(256) void k_degree(const int* __restrict__ src, const int* __restrict__ dst,
    uint32_t* __restrict__ bits, int* __restrict__ dego, int* __restrict__ degi,
    uint32_t* __restrict__ scal_u) {
  int e = blockIdx.x * 256 + threadIdx.x;
  int s = src[e], d = dst[e];
  atomicAdd(&dego[s], 1);
  atomicAdd(&degi[d], 1);
  unsigned idx = (unsigned)s * 8192u + (unsigned)d;
  unsigned bit = 1u << (idx & 31);
  unsigned old = atomicOr(&bits[idx >> 5], bit);
  bool isnew = !(old & bit);
  unsigned long long b = __ballot(isnew);
  if ((threadIdx.x & 63) == 0) atomicAdd(&scal_u[2], (unsigned)__popcll(b));
}

__global__ __launch_bounds__(256) void k_norms(const int* __restrict__ dego, const int* __restrict__ degi,
                                               float* __restrict__ nsrc, float* __restrict__ ndst) {
  int i = blockIdx.x * 256 + threadIdx.x;
  if (i >= N) return;
  int a = dego[i], b = degi[i];
  nsrc[i] = a > 0 ? 1.0f / sqrtf((float)a) : 0.0f;
  ndst[i] = b > 0 ? 1.0f / sqrtf((float)b) : 0.0f;
}

// exclusive scan of deg_in -> row_ptr, cursor (single block, 1024 threads, 8 elems each)
__global__ __launch_bounds__(1024) void k_scan(const int* __restrict__ degi, int* __restrict__ rowptr,
                                               int* __restrict__ cursor) {
  __shared__ int sh[1024];
  int tid = threadIdx.x;
  int base = tid * 8;
  int v[8];
  int s = 0;
#pragma unroll
  for (int j = 0; j < 8; ++j) { v[j] = degi[base + j]; s += v[j]; }
  sh[tid] = s;
  __syncthreads();
  for (int off = 1; off < 1024; off <<= 1) {
    int t = (tid >= off) ? sh[tid - off] : 0;
    __syncthreads();
    sh[tid] += t;
    __syncthreads();
  }
  int run = (tid == 0) ? 0 : sh[tid - 1];
#pragma unroll
  for (int j = 0; j < 8; ++j) { rowptr[base + j] = run; cursor[base + j] = run; run += v[j]; }
  if (tid == 1023) rowptr[N] = run;
}

__global__ __launch_bounds__(256) void k_scatter(const int* __restrict__ src, const int* __restrict__ dst,
                                                 int* __restrict__ cursor, int* __restrict__ csr) {
  int e = blockIdx.x * 256 + threadIdx.x;
  int d = dst[e];
  int pos = atomicAdd(&cursor[d], 1);
  csr[pos] = src[e];
}

// out[i,:] = in[i,:] * norm[i]  (float4 over N*32)
__global__ __launch_bounds__(256) void k_scale(const float4* __restrict__ in, const float* __restrict__ norm,
                                               float4* __restrict__ out) {
  int i = blockIdx.x * 256 + threadIdx.x;
  if (i >= N * 32) return;
  float s = norm[i >> 5];
  float4 v = in[i];
  v.x *= s; v.y *= s; v.z *= s; v.w *= s;
  out[i] = v;
}

// CSR gather-aggregate: out[row,:] = (sum over in-edges of tmp[src,:]) * ndst[row]
__global__ __launch_bounds__(128) void k_aggregate(const int* __restrict__ rowptr, const int* __restrict__ csr,
    const float* __restrict__ tmp, const float* __restrict__ ndst, float* __restrict__ out) {
  int row = blockIdx.x, t = threadIdx.x;
  int e0 = rowptr[row], e1 = rowptr[row + 1];
  float acc = 0.f;
  int e = e0;
  for (; e + 4 <= e1; e += 4) {
    int s0 = csr[e], s1 = csr[e + 1], s2 = csr[e + 2], s3 = csr[e + 3];
    acc += tmp[s0 * 128 + t];
    acc += tmp[s1 * 128 + t];
    acc += tmp[s2 * 128 + t];
    acc += tmp[s3 * 128 + t];
  }
  for (; e < e1; ++e) acc += tmp[csr[e] * 128 + t];
  out[row * 128 + t] = acc * ndst[row];
}

// row-wise l2 normalize (one wave per row). out_extra: optional scalar-store copy (misaligned base ok)
__global__ __launch_bounds__(256) void k_l2norm(const float* __restrict__ in, float* __restrict__ out_al,
                                                float* __restrict__ out_extra, int rows) {
  int wave = threadIdx.x >> 6, lane = threadIdx.x & 63;
  int row = blockIdx.x * 4 + wave;
  if (row >= rows) return;
  float2 v = ((const float2*)in)[row * 64 + lane];
  float ss = v.x * v.x + v.y * v.y;
#pragma unroll
  for (int o = 32; o > 0; o >>= 1) ss += __shfl_xor(ss, o);
  float den = fmaxf(sqrtf(ss), 1e-12f);
  float ox = v.x / den, oy = v.y / den;
  ((float2*)out_al)[row * 64 + lane] = make_float2(ox, oy);
  if (out_extra != nullptr) {
    out_extra[row * 128 + 2 * lane] = ox;
    out_extra[row * 128 + 2 * lane + 1] = oy;
  }
}

// ---------------- small matmul: out[M,CO] = A[M,128] @ W[128,CO] + bias (+relu) ----------------
template <int CO, bool RELU>
__global__ __launch_bounds__(256, 2) void k_mm(const float* __restrict__ A, const float* __restrict__ W,
    const float* __restrict__ bias, float* __restrict__ out) {
  constexpr int CG = CO / 4;       // col f4 groups
  constexpr int RG = 256 / CG;     // row groups
  constexpr int TR = RG * 4;       // tile rows (CO=128 -> 32, CO=64 -> 64)
  constexpr int WIT = (64 * CG) / 256;
  __shared__ __align__(16) float Al[TR * 128];
  __shared__ __align__(16) float Wl[64 * CO];
  int tid = threadIdx.x;
  int cg = tid % CG, rg = tid / CG;
  int rbase = blockIdx.x * TR;
#pragma unroll
  for (int it = 0; it < TR / 8; ++it) {
    int idx = tid + it * 256;
    int r = idx >> 5, c = idx & 31;
    *(float4*)&Al[r * 128 + c * 4] = *(const float4*)&A[(rbase + r) * 128 + c * 4];
  }
  float acc[4][4] = {};
  for (int kc = 0; kc < 128; kc += 64) {
    __syncthreads();
#pragma unroll
    for (int it = 0; it < WIT; ++it) {
      int idx = tid + it * 256;
      int r = idx / CG, c = idx % CG;
      *(float4*)&Wl[r * CO + c * 4] = *(const float4*)&W[(kc + r) * CO + c * 4];
    }
    __syncthreads();
#pragma unroll
    for (int k = 0; k < 64; ++k) {
      float4 w4 = *(const float4*)&Wl[k * CO + cg * 4];
#pragma unroll
      for (int i = 0; i < 4; ++i) {
        float a = Al[(rg * 4 + i) * 128 + kc + k];
        acc[i][0] += a * w4.x; acc[i][1] += a * w4.y; acc[i][2] += a * w4.z; acc[i][3] += a * w4.w;
      }
    }
  }
  float4 b4 = *(const float4*)&bias[cg * 4];
#pragma unroll
  for (int i = 0; i < 4; ++i) {
    float4 o;
    o.x = acc[i][0] + b4.x; o.y = acc[i][1] + b4.y; o.z = acc[i][2] + b4.z; o.w = acc[i][3] + b4.w;
    if (RELU) { o.x = fmaxf(o.x, 0.f); o.y = fmaxf(o.y, 0.f); o.z = fmaxf(o.z, 0.f); o.w = fmaxf(o.w, 0.f); }
    *(float4*)&out[(rbase + rg * 4 + i) * CO + cg * 4] = o;
  }
}

// ---------------- big NT GEMM: C = A @ B^T, 128x128 tile, 8x8 micro-tile ----------------
// ADJQ=false: writes dist + fused row argmax.  ADJQ=true: upper-triangle blocks only,
// fused sum/sumsq/min/max/edge-masked sum (adj never materialized).
// NOTE round 2 post-mortem: __launch_bounds__(256,2) capped VGPRs at 128 and spilled
// acc[8][8] to scratch -> 7.2 GB HBM traffic/dispatch, VALUBusy 4.9%. Default bounds:
// ~170 VGPRs, no spill; LDS (64 KB) still allows 2 blocks/CU.
template <bool ADJQ>
__global__ __launch_bounds__(256) void k_gemm(const float* __restrict__ A, const float* __restrict__ B,
    float* __restrict__ dout, unsigned long long* __restrict__ amax, const uint32_t* __restrict__ bits,
    double* __restrict__ scal_d, uint32_t* __restrict__ scal_u) {
  int bx = blockIdx.x, by = blockIdx.y;
  if (ADJQ && bx < by) return;   // symmetry: only col-tile >= row-tile
  int rbase = by * 128, cbase = bx * 128;
  __shared__ __align__(16) float Al[128 * 64];
  __shared__ __align__(16) float Bl[128 * 64];
  int tid = threadIdx.x;
  int tx = tid & 15, ty = tid >> 4;
  float acc[8][8];
#pragma unroll
  for (int i = 0; i < 8; ++i)
#pragma unroll
    for (int j = 0; j < 8; ++j) acc[i][j] = 0.f;

  for (int kc = 0; kc < 128; kc += 64) {
#pragma unroll
    for (int it = 0; it < 8; ++it) {
      int idx = tid + it * 256;
      int r = idx >> 4, c = idx & 15;
      // XOR swizzle: slot4 = c ^ (r&15) -> conflict-free b128 reads in the inner loop
      float4 av = *(const float4*)&A[(rbase + r) * 128 + kc + c * 4];
      *(float4*)&Al[r * 64 + ((c ^ (r & 15)) << 2)] = av;
      float4 bv = *(const float4*)&B[(cbase + r) * 128 + kc + c * 4];
      *(float4*)&Bl[r * 64 + ((c ^ (r & 15)) << 2)] = bv;
    }
    __syncthreads();
#pragma unroll
    for (int k4 = 0; k4 < 16; ++k4) {
      float4 a[8], b[8];
      int sa = ((k4 ^ ty) << 2);
      int sb = ((k4 ^ tx) << 2);
#pragma unroll
      for (int i = 0; i < 8; ++i) a[i] = *(const float4*)&Al[(ty + (i << 4)) * 64 + sa];
#pragma unroll
      for (int j = 0; j < 8; ++j) b[j] = *(const float4*)&Bl[(tx + (j << 4)) * 64 + sb];
#pragma unroll
      for (int i = 0; i < 8; ++i)
#pragma unroll
        for (int j = 0; j < 8; ++j)
          acc[i][j] += a[i].x * b[j].x + a[i].y * b[j].y + a[i].z * b[j].z + a[i].w * b[j].w;
    }
    __syncthreads();
  }

  if (!ADJQ) {
    float bestv[8];
    int bestc[8];
#pragma unroll
    for (int i = 0; i < 8; ++i) { bestv[i] = -3.4e38f; bestc[i] = 0; }
#pragma unroll
    for (int i = 0; i < 8; ++i) {
      int row = rbase + ty + (i << 4);
#pragma unroll
      for (int j = 0; j < 8; ++j) {
        int col = cbase + tx + (j << 4);
        float v = acc[i][j];
        dout[row * 4096 + col] = v;   // scalar store: dist base is float-misaligned for float4
        if (v > bestv[i]) { bestv[i] = v; bestc[i] = col; }  // strict > keeps lowest col (np tie rule)
      }
    }
    unsigned long long* sc = (unsigned long long*)Al;  // reuse (safe: past last barrier, Al unread)
#pragma unroll
    for (int i = 0; i < 8; ++i)
      sc[(ty + (i << 4)) * 16 + tx] =
          (((unsigned long long)fmap(bestv[i])) << 32) | (unsigned long long)(0xFFFFFFFFu - (unsigned)bestc[i]);
    __syncthreads();
    if (tid < 128) {
      unsigned long long m = 0ull;
#pragma unroll
      for (int k = 0; k < 16; ++k) {
        unsigned long long t = sc[tid * 16 + k];
        m = t > m ? t : m;
      }
      atomicMax(&amax[rbase + tid], m);
    }
  } else {
    // stage adjacency bit tile (both orientations) into LDS
    uint32_t* bl = (uint32_t*)Al;   // bl[lr*4 + w]  : bits for (rbase+lr, cbase..cbase+127)
    uint32_t* blT = bl + 512;       // blT[lc*4 + w] : bits for (cbase+lc, rbase..rbase+127)
#pragma unroll
    for (int it = 0; it < 2; ++it) {
      int idx = tid + it * 256;  // 0..511
      int r = idx >> 2, wq = idx & 3;
      bl[idx] = bits[(rbase + r) * 256 + (cbase >> 5) + wq];
      blT[idx] = bits[(cbase + r) * 256 + (rbase >> 5) + wq];
    }
    __syncthreads();
    double lsum = 0.0, lsq = 0.0, les = 0.0;
    float lmin = 3.4e38f, lmax = -3.4e38f;
    bool diag = (bx == by);
#pragma unroll
    for (int i = 0; i < 8; ++i) {
      int lr = ty + (i << 4);
      int row = rbase + lr;
#pragma unroll
      for (int j = 0; j < 8; ++j) {
        int lc = tx + (j << 4);
        int col = cbase + lc;
        if (diag && col < row) continue;   // only upper triangle (incl. diagonal)
        float v = acc[i][j];
        double dv = (double)v;
        double wgt = (col == row) ? 1.0 : 2.0;
        lsum += wgt * dv;
        lsq += wgt * dv * dv;
        lmin = fminf(lmin, v);
        lmax = fmaxf(lmax, v);
        unsigned eb = (bl[lr * 4 + (lc >> 5)] >> (lc & 31)) & 1u;
        if (col != row) eb += (blT[lc * 4 + (lr >> 5)] >> (lr & 31)) & 1u;
        if (eb) les += (double)eb * dv;
      }
    }
#pragma unroll
    for (int o = 32; o > 0; o >>= 1) {
      lsum += __shfl_xor(lsum, o);
      lsq += __shfl_xor(lsq, o);
      les += __shfl_xor(les, o);
      lmin = fminf(lmin, __shfl_xor(lmin, o));
      lmax = fmaxf(lmax, __shfl_xor(lmax, o));
    }
    if ((tid & 63) == 0) {
      atomicAdd(&scal_d[0], lsum);
      atomicAdd(&scal_d[1], lsq);
      atomicAdd(&scal_d[2], les);
      atomicMin(&scal_u[0], fmap(lmin));
      atomicMax(&scal_u[1], fmap(lmax));
    }
  }
}

// gather chosen codes -> quantized output; accumulate commit loss sum
__global__ __launch_bounds__(128) void k_q(const unsigned long long* __restrict__ amax,
    const float* __restrict__ cnws, const float* __restrict__ h1, float* __restrict__ qout,
    double* __restrict__ scal_d) {
  int row = blockIdx.x, t = threadIdx.x;
  unsigned long long key = amax[row];
  int col = (int)(0xFFFFFFFFu - (uint32_t)(key & 0xFFFFFFFFull));
  float q = cnws[col * 128 + t];
  qout[row * 128 + t] = q;
  float dd = q - h1[row * 128 + t];
  float ss = dd * dd;
#pragma unroll
  for (int o = 32; o > 0; o >>= 1) ss += __shfl_xor(ss, o);
  __shared__ float p[2];
  if ((t & 63) == 0) p[t >> 6] = ss;
  __syncthreads();
  if (t == 0) atomicAdd(&scal_d[3], (double)(p[0] + p[1]));
}

// sum of squared diff (h1 - quantized_node) -> scal_d[4]
__global__ __launch_bounds__(256) void k_sqdiff(const float4* __restrict__ a, const float4* __restrict__ b,
                                                double* __restrict__ scal_d) {
  int i = blockIdx.x * 256 + threadIdx.x;
  float s = 0.f;
  const int total = N * 32;
  for (; i < total; i += gridDim.x * 256) {
    float4 x = a[i], y = b[i];
    float d0 = x.x - y.x, d1 = x.y - y.y, d2 = x.z - y.z, d3 = x.w - y.w;
    s += d0 * d0 + d1 * d1 + d2 * d2 + d3 * d3;
  }
#pragma unroll
  for (int o = 32; o > 0; o >>= 1) s += __shfl_xor(s, o);
  if ((threadIdx.x & 63) == 0) atomicAdd(&scal_d[4], (double)s);
}

// final scalar combination
__global__ void k_loss(const double* __restrict__ scal_d, const uint32_t* __restrict__ scal_u,
                       float* __restrict__ o_loss) {
  if (threadIdx.x != 0 || blockIdx.x != 0) return;
  double sum = scal_d[0], sq = scal_d[1], es = scal_d[2];
  double mn = (double)funmap(scal_u[0]);
  double mx = (double)funmap(scal_u[1]);
  double U = (double)scal_u[2];
  const double N2 = 67108864.0;  // 8192^2
  double s = 1.0 / (mx - mn);
  // sum over all (i,j) of (adj - (aq-mn)*s)^2, with adj=1 on U unique edge slots
  double mean = (s * s * (sq - 2.0 * mn * sum + mn * mn * N2) - 2.0 * s * (es - mn * U) + U) / N2;
  double edge = sqrt(mean);
  double commit = 0.25 * scal_d[3] / 1048576.0;
  double frec = scal_d[4] / 1048576.0;
  *o_loss = (float)(frec + edge + commit);
}

extern "C" void kernel_launch(void* const* d_in, const int* in_sizes, int n_in,
                              void* d_out, int out_size, void* d_ws, size_t ws_size,
                              hipStream_t stream) {
  (void)in_sizes; (void)n_in; (void)out_size;
  const float* feats = (const float*)d_in[0];
  const int* src = (const int*)d_in[1];
  const int* dst = (const int*)d_in[2];
  const float* W1 = (const float*)d_in[3];
  const float* b1 = (const float*)d_in[4];
  const float* W2 = (const float*)d_in[5];
  const float* b2 = (const float*)d_in[6];
  const float* dec1W = (const float*)d_in[7];
  const float* dec1b = (const float*)d_in[8];
  const float* dec2W = (const float*)d_in[9];
  const float* dec2b = (const float*)d_in[10];
  const float* linW = (const float*)d_in[11];
  const float* linb = (const float*)d_in[12];
  const float* codebook = (const float*)d_in[13];

  float* out = (float*)d_out;
  float* o_h1 = out;                    // [N,128]
  float* o_q = out + 1048576;           // [N,128]
  float* o_h3 = out + 2097152;          // [N,128]
  float* o_out = out + 3145728;         // [N,64]
  float* o_loss = out + 3670016;        // scalar
  float* o_dist = out + 3670017;        // [N,4096] (float-misaligned base!)
  float* o_cn = out + 37224449;         // [C,128]  (float-misaligned base!)

  char* w = (char*)d_ws;
  size_t off = 0;
  auto alloc = [&](size_t b) { char* p = w + off; off = (off + b + 255) & ~(size_t)255; return p; };
  uint32_t* bits = (uint32_t*)alloc(8388608);            // N*N/8 adjacency bitmask
  int* dego = (int*)alloc(N * 4);
  int* degi = (int*)alloc(N * 4);
  unsigned long long* amax = (unsigned long long*)alloc(N * 8);
  double* scal_d = (double*)alloc(256);                  // [0]=sum [1]=sumsq [2]=edge-sum [3]=commit [4]=frec
  uint32_t* scal_u = (uint32_t*)(scal_d + 8);            // [0]=min [1]=max [2]=U
  size_t zero_bytes = off;                               // everything above must start at 0
  int* rowptr = (int*)alloc((N + 1) * 4);
  int* cursor = (int*)alloc(N * 4);
  int* csr = (int*)alloc(E * 4);
  float* nsrc = (float*)alloc(N * 4);
  float* ndst = (float*)alloc(N * 4);
  float* tmp = (float*)alloc((size_t)N * D * 4);
  float* agg = (float*)alloc((size_t)N * D * 4);
  float* xn = (float*)alloc((size_t)N * D * 4);
  float* cnws = (float*)alloc((size_t)C * D * 4);        // aligned copy of cn
  float* qe = (float*)alloc((size_t)N * D * 4);
  float* qn = (float*)alloc((size_t)N * D * 4);
  if (ws_size < off) return;  // insufficient scratch (will fail validation loudly)

  hipMemsetAsync(d_ws, 0, zero_bytes, stream);
  k_init<<<1, 256, 0, stream>>>(scal_u);

  // graph structure
  k_degree<<<E / 256, 256, 0, stream>>>(src, dst, bits, dego, degi, scal_u);
  k_norms<<<N / 256, 256, 0, stream>>>(dego, degi, nsrc, ndst);
  k_scan<<<1, 1024, 0, stream>>>(degi, rowptr, cursor);
  k_scatter<<<E / 256, 256, 0, stream>>>(src, dst, cursor, csr);

  // conv1: h1 = relu((scatter(feats*nsrc)*ndst) @ W1 + b1)
  k_scale<<<N * 32 / 256, 256, 0, stream>>>((const float4*)feats, nsrc, (float4*)tmp);
  k_aggregate<<<N, 128, 0, stream>>>(rowptr, csr, tmp, ndst, agg);
  k_mm<128, true><<<N / 32, 256, 0, stream>>>(agg, W1, b1, o_h1);

  // VQ: cn, xn, dist (+argmax), q, commit loss
  k_l2norm<<<C / 4, 256, 0, stream>>>(codebook, cnws, o_cn, C);
  k_l2norm<<<N / 4, 256, 0, stream>>>(o_h1, xn, nullptr, N);
  k_gemm<false><<<dim3(C / 128, N / 128), 256, 0, stream>>>(xn, cnws, o_dist, amax, nullptr, nullptr, nullptr);
  k_q<<<N, 128, 0, stream>>>(amax, cnws, o_h1, o_q, scal_d);

  // decoders
  k_mm<128, false><<<N / 32, 256, 0, stream>>>(o_q, dec1W, dec1b, qe);
  k_mm<128, false><<<N / 32, 256, 0, stream>>>(o_q, dec2W, dec2b, qn);
  k_sqdiff<<<512, 256, 0, stream>>>((const float4*)o_h1, (const float4*)qn, scal_d);

  // adjacency reconstruction loss (fused reductions, upper-triangle only)
  k_gemm<true><<<dim3(N / 128, N / 128), 256, 0, stream>>>(qe, qe, nullptr, nullptr, bits, scal_d, scal_u);

  // conv2 on quantized_edge + linear head
  k_scale<<<N * 32 / 256, 256, 0, stream>>>((const float4*)qe, nsrc, (float4*)tmp);
  k_aggregate<<<N, 128, 0, stream>>>(rowptr, csr, tmp, ndst, agg);
  k_mm<128, true><<<N / 32, 256, 0, stream>>>(agg, W2, b2, o_h3);
  k_mm<64, false><<<N / 64, 256, 0, stream>>>(o_h3, linW, linb, o_out);

  k_loss<<<1, 64, 0, stream>>>(scal_d, scal_u, o_loss);
}

// Round 4
// 960.662 us; speedup vs baseline: 5.0390x; 3.3056x over previous
//
#include <hip/hip_runtime.h>
#include <cstdint>

// Problem constants
constexpr int N = 8192, E = 262144, D = 128, O = 64, C = 4096;

#define DEV __device__ __forceinline__

// orderable-uint mapping for float atomicMin/Max and packed argmax
DEV unsigned fmap(float f) {
  unsigned u = __float_as_uint(f);
  return (u & 0x80000000u) ? ~u : (u | 0x80000000u);
}
DEV float funmap(unsigned u) {
  unsigned b = (u & 0x80000000u) ? (u & 0x7FFFFFFFu) : ~u;
  return __uint_as_float(b);
}

// ---------------- setup kernels ----------------

__global__ __launch_bounds__(256) void k_init(uint32_t* scal_u) {
  if (threadIdx.x == 0 && blockIdx.x == 0) scal_u[0] = 0xFFFFFFFFu;  // min slot
}

// degrees + adjacency bitmask + unique-edge count
__global__ __launch_bounds__(256) void k_degree(const int* __restrict__ src, const int* __restrict__ dst,
    uint32_t* __restrict__ bits, int* __restrict__ dego, int* __restrict__ degi,
    uint32_t* __restrict__ scal_u) {
  int e = blockIdx.x * 256 + threadIdx.x;
  int s = src[e], d = dst[e];
  atomicAdd(&dego[s], 1);
  atomicAdd(&degi[d], 1);
  unsigned idx = (unsigned)s * 8192u + (unsigned)d;
  unsigned bit = 1u << (idx & 31);
  unsigned old = atomicOr(&bits[idx >> 5], bit);
  bool isnew = !(old & bit);
  unsigned long long b = __ballot(isnew);
  if ((threadIdx.x & 63) == 0) atomicAdd(&scal_u[2], (unsigned)__popcll(b));
}

__global__ __launch_bounds__(256) void k_norms(const int* __restrict__ dego, const int* __restrict__ degi,
                                               float* __restrict__ nsrc, float* __restrict__ ndst) {
  int i = blockIdx.x * 256 + threadIdx.x;
  if (i >= N) return;
  int a = dego[i], b = degi[i];
  nsrc[i] = a > 0 ? 1.0f / sqrtf((float)a) : 0.0f;
  ndst[i] = b > 0 ? 1.0f / sqrtf((float)b) : 0.0f;
}

// exclusive scan of deg_in -> row_ptr, cursor (single block, 1024 threads, 8 elems each)
__global__ __launch_bounds__(1024) void k_scan(const int* __restrict__ degi, int* __restrict__ rowptr,
                                               int* __restrict__ cursor) {
  __shared__ int sh[1024];
  int tid = threadIdx.x;
  int base = tid * 8;
  int v[8];
  int s = 0;
#pragma unroll
  for (int j = 0; j < 8; ++j) { v[j] = degi[base + j]; s += v[j]; }
  sh[tid] = s;
  __syncthreads();
  for (int off = 1; off < 1024; off <<= 1) {
    int t = (tid >= off) ? sh[tid - off] : 0;
    __syncthreads();
    sh[tid] += t;
    __syncthreads();
  }
  int run = (tid == 0) ? 0 : sh[tid - 1];
#pragma unroll
  for (int j = 0; j < 8; ++j) { rowptr[base + j] = run; cursor[base + j] = run; run += v[j]; }
  if (tid == 1023) rowptr[N] = run;
}

__global__ __launch_bounds__(256) void k_scatter(const int* __restrict__ src, const int* __restrict__ dst,
                                                 int* __restrict__ cursor, int* __restrict__ csr) {
  int e = blockIdx.x * 256 + threadIdx.x;
  int d = dst[e];
  int pos = atomicAdd(&cursor[d], 1);
  csr[pos] = src[e];
}

// out[i,:] = in[i,:] * norm[i]  (float4 over N*32)
__global__ __launch_bounds__(256) void k_scale(const float4* __restrict__ in, const float* __restrict__ norm,
                                               float4* __restrict__ out) {
  int i = blockIdx.x * 256 + threadIdx.x;
  if (i >= N * 32) return;
  float s = norm[i >> 5];
  float4 v = in[i];
  v.x *= s; v.y *= s; v.z *= s; v.w *= s;
  out[i] = v;
}

// CSR gather-aggregate: out[row,:] = (sum over in-edges of tmp[src,:]) * ndst[row]
__global__ __launch_bounds__(128) void k_aggregate(const int* __restrict__ rowptr, const int* __restrict__ csr,
    const float* __restrict__ tmp, const float* __restrict__ ndst, float* __restrict__ out) {
  int row = blockIdx.x, t = threadIdx.x;
  int e0 = rowptr[row], e1 = rowptr[row + 1];
  float acc = 0.f;
  int e = e0;
  for (; e + 4 <= e1; e += 4) {
    int s0 = csr[e], s1 = csr[e + 1], s2 = csr[e + 2], s3 = csr[e + 3];
    acc += tmp[s0 * 128 + t];
    acc += tmp[s1 * 128 + t];
    acc += tmp[s2 * 128 + t];
    acc += tmp[s3 * 128 + t];
  }
  for (; e < e1; ++e) acc += tmp[csr[e] * 128 + t];
  out[row * 128 + t] = acc * ndst[row];
}

// row-wise l2 normalize (one wave per row). out_extra: optional scalar-store copy (misaligned base ok)
__global__ __launch_bounds__(256) void k_l2norm(const float* __restrict__ in, float* __restrict__ out_al,
                                                float* __restrict__ out_extra, int rows) {
  int wave = threadIdx.x >> 6, lane = threadIdx.x & 63;
  int row = blockIdx.x * 4 + wave;
  if (row >= rows) return;
  float2 v = ((const float2*)in)[row * 64 + lane];
  float ss = v.x * v.x + v.y * v.y;
#pragma unroll
  for (int o = 32; o > 0; o >>= 1) ss += __shfl_xor(ss, o);
  float den = fmaxf(sqrtf(ss), 1e-12f);
  float ox = v.x / den, oy = v.y / den;
  ((float2*)out_al)[row * 64 + lane] = make_float2(ox, oy);
  if (out_extra != nullptr) {
    out_extra[row * 128 + 2 * lane] = ox;
    out_extra[row * 128 + 2 * lane + 1] = oy;
  }
}

// ---------------- small matmul: out[M,CO] = A[M,128] @ W[128,CO] + bias (+relu) ----------------
template <int CO, bool RELU>
__global__ __launch_bounds__(256, 2) void k_mm(const float* __restrict__ A, const float* __restrict__ W,
    const float* __restrict__ bias, float* __restrict__ out) {
  constexpr int CG = CO / 4;       // col f4 groups
  constexpr int RG = 256 / CG;     // row groups
  constexpr int TR = RG * 4;       // tile rows (CO=128 -> 32, CO=64 -> 64)
  constexpr int WIT = (64 * CG) / 256;
  __shared__ __align__(16) float Al[TR * 128];
  __shared__ __align__(16) float Wl[64 * CO];
  int tid = threadIdx.x;
  int cg = tid % CG, rg = tid / CG;
  int rbase = blockIdx.x * TR;
#pragma unroll
  for (int it = 0; it < TR / 8; ++it) {
    int idx = tid + it * 256;
    int r = idx >> 5, c = idx & 31;
    *(float4*)&Al[r * 128 + c * 4] = *(const float4*)&A[(rbase + r) * 128 + c * 4];
  }
  float acc[4][4] = {};
  for (int kc = 0; kc < 128; kc += 64) {
    __syncthreads();
#pragma unroll
    for (int it = 0; it < WIT; ++it) {
      int idx = tid + it * 256;
      int r = idx / CG, c = idx % CG;
      *(float4*)&Wl[r * CO + c * 4] = *(const float4*)&W[(kc + r) * CO + c * 4];
    }
    __syncthreads();
#pragma unroll
    for (int k = 0; k < 64; ++k) {
      float4 w4 = *(const float4*)&Wl[k * CO + cg * 4];
#pragma unroll
      for (int i = 0; i < 4; ++i) {
        float a = Al[(rg * 4 + i) * 128 + kc + k];
        acc[i][0] += a * w4.x; acc[i][1] += a * w4.y; acc[i][2] += a * w4.z; acc[i][3] += a * w4.w;
      }
    }
  }
  float4 b4 = *(const float4*)&bias[cg * 4];
#pragma unroll
  for (int i = 0; i < 4; ++i) {
    float4 o;
    o.x = acc[i][0] + b4.x; o.y = acc[i][1] + b4.y; o.z = acc[i][2] + b4.z; o.w = acc[i][3] + b4.w;
    if (RELU) { o.x = fmaxf(o.x, 0.f); o.y = fmaxf(o.y, 0.f); o.z = fmaxf(o.z, 0.f); o.w = fmaxf(o.w, 0.f); }
    *(float4*)&out[(rbase + rg * 4 + i) * CO + cg * 4] = o;
  }
}

// ---------------- big NT GEMM: C = A @ B^T, 128x128 tile, 8x8 micro-tile ----------------
// ADJQ=false: writes dist + fused row argmax.  ADJQ=true: upper-triangle blocks only,
// fused sum/sumsq/min/max/edge-masked sum (adj never materialized).
// Round-2 post-mortem: __launch_bounds__(256,2) -> 128-VGPR cap -> acc spill -> 7.2 GB HBM.
// Round-3 post-mortem: default bounds hit the 256-VGPR arch max and STILL spilled (4.5 GB,
// WRITE>FETCH): compiler fully unrolled the 16x k4 loop and pipelined several a[8]+b[8]
// sets (64 VGPRs each) across iterations. Fix: #pragma unroll 1 on the k4 loop + per-j
// b load, capping live set at acc(64)+a(32)+b(4)+addr ~ 110. Cross-wave TLP (8 waves/CU)
// hides LDS latency instead of in-wave pipelining.
template <bool ADJQ>
__global__ __launch_bounds__(256) void k_gemm(const float* __restrict__ A, const float* __restrict__ B,
    float* __restrict__ dout, unsigned long long* __restrict__ amax, const uint32_t* __restrict__ bits,
    double* __restrict__ scal_d, uint32_t* __restrict__ scal_u) {
  int bx = blockIdx.x, by = blockIdx.y;
  if (ADJQ && bx < by) return;   // symmetry: only col-tile >= row-tile
  int rbase = by * 128, cbase = bx * 128;
  __shared__ __align__(16) float Al[128 * 64];
  __shared__ __align__(16) float Bl[128 * 64];
  int tid = threadIdx.x;
  int tx = tid & 15, ty = tid >> 4;
  float acc[8][8];
#pragma unroll
  for (int i = 0; i < 8; ++i)
#pragma unroll
    for (int j = 0; j < 8; ++j) acc[i][j] = 0.f;

  for (int kc = 0; kc < 128; kc += 64) {
#pragma unroll
    for (int it = 0; it < 8; ++it) {
      int idx = tid + it * 256;
      int r = idx >> 4, c = idx & 15;
      // XOR swizzle: slot4 = c ^ (r&15) -> conflict-free b128 reads in the inner loop
      float4 av = *(const float4*)&A[(rbase + r) * 128 + kc + c * 4];
      *(float4*)&Al[r * 64 + ((c ^ (r & 15)) << 2)] = av;
      float4 bv = *(const float4*)&B[(cbase + r) * 128 + kc + c * 4];
      *(float4*)&Bl[r * 64 + ((c ^ (r & 15)) << 2)] = bv;
    }
    __syncthreads();
#pragma unroll 1   // CRITICAL: prevent unroll-16 + pipelining -> VGPR spill (see header note)
    for (int k4 = 0; k4 < 16; ++k4) {
      float4 a[8];
      int sa = ((k4 ^ ty) << 2);
      int sb = ((k4 ^ tx) << 2);
#pragma unroll
      for (int i = 0; i < 8; ++i) a[i] = *(const float4*)&Al[(ty + (i << 4)) * 64 + sa];
#pragma unroll
      for (int j = 0; j < 8; ++j) {
        float4 b = *(const float4*)&Bl[(tx + (j << 4)) * 64 + sb];
#pragma unroll
        for (int i = 0; i < 8; ++i)
          acc[i][j] += a[i].x * b.x + a[i].y * b.y + a[i].z * b.z + a[i].w * b.w;
      }
    }
    __syncthreads();
  }

  if (!ADJQ) {
    float bestv[8];
    int bestc[8];
#pragma unroll
    for (int i = 0; i < 8; ++i) { bestv[i] = -3.4e38f; bestc[i] = 0; }
#pragma unroll
    for (int i = 0; i < 8; ++i) {
      int row = rbase + ty + (i << 4);
#pragma unroll
      for (int j = 0; j < 8; ++j) {
        int col = cbase + tx + (j << 4);
        float v = acc[i][j];
        dout[row * 4096 + col] = v;   // scalar store: dist base is float-misaligned for float4
        if (v > bestv[i]) { bestv[i] = v; bestc[i] = col; }  // strict > keeps lowest col (np tie rule)
      }
    }
    unsigned long long* sc = (unsigned long long*)Al;  // reuse (safe: past last barrier, Al unread)
#pragma unroll
    for (int i = 0; i < 8; ++i)
      sc[(ty + (i << 4)) * 16 + tx] =
          (((unsigned long long)fmap(bestv[i])) << 32) | (unsigned long long)(0xFFFFFFFFu - (unsigned)bestc[i]);
    __syncthreads();
    if (tid < 128) {
      unsigned long long m = 0ull;
#pragma unroll
      for (int k = 0; k < 16; ++k) {
        unsigned long long t = sc[tid * 16 + k];
        m = t > m ? t : m;
      }
      atomicMax(&amax[rbase + tid], m);
    }
  } else {
    // stage adjacency bit tile (both orientations) into LDS
    uint32_t* bl = (uint32_t*)Al;   // bl[lr*4 + w]  : bits for (rbase+lr, cbase..cbase+127)
    uint32_t* blT = bl + 512;       // blT[lc*4 + w] : bits for (cbase+lc, rbase..rbase+127)
#pragma unroll
    for (int it = 0; it < 2; ++it) {
      int idx = tid + it * 256;  // 0..511
      int r = idx >> 2, wq = idx & 3;
      bl[idx] = bits[(rbase + r) * 256 + (cbase >> 5) + wq];
      blT[idx] = bits[(cbase + r) * 256 + (rbase >> 5) + wq];
    }
    __syncthreads();
    double lsum = 0.0, lsq = 0.0, les = 0.0;
    float lmin = 3.4e38f, lmax = -3.4e38f;
    bool diag = (bx == by);
#pragma unroll
    for (int i = 0; i < 8; ++i) {
      int lr = ty + (i << 4);
      int row = rbase + lr;
#pragma unroll
      for (int j = 0; j < 8; ++j) {
        int lc = tx + (j << 4);
        int col = cbase + lc;
        if (diag && col < row) continue;   // only upper triangle (incl. diagonal)
        float v = acc[i][j];
        double dv = (double)v;
        double wgt = (col == row) ? 1.0 : 2.0;
        lsum += wgt * dv;
        lsq += wgt * dv * dv;
        lmin = fminf(lmin, v);
        lmax = fmaxf(lmax, v);
        unsigned eb = (bl[lr * 4 + (lc >> 5)] >> (lc & 31)) & 1u;
        if (col != row) eb += (blT[lc * 4 + (lr >> 5)] >> (lr & 31)) & 1u;
        if (eb) les += (double)eb * dv;
      }
    }
#pragma unroll
    for (int o = 32; o > 0; o >>= 1) {
      lsum += __shfl_xor(lsum, o);
      lsq += __shfl_xor(lsq, o);
      les += __shfl_xor(les, o);
      lmin = fminf(lmin, __shfl_xor(lmin, o));
      lmax = fmaxf(lmax, __shfl_xor(lmax, o));
    }
    if ((tid & 63) == 0) {
      atomicAdd(&scal_d[0], lsum);
      atomicAdd(&scal_d[1], lsq);
      atomicAdd(&scal_d[2], les);
      atomicMin(&scal_u[0], fmap(lmin));
      atomicMax(&scal_u[1], fmap(lmax));
    }
  }
}

// gather chosen codes -> quantized output; accumulate commit loss sum
__global__ __launch_bounds__(128) void k_q(const unsigned long long* __restrict__ amax,
    const float* __restrict__ cnws, const float* __restrict__ h1, float* __restrict__ qout,
    double* __restrict__ scal_d) {
  int row = blockIdx.x, t = threadIdx.x;
  unsigned long long key = amax[row];
  int col = (int)(0xFFFFFFFFu - (uint32_t)(key & 0xFFFFFFFFull));
  float q = cnws[col * 128 + t];
  qout[row * 128 + t] = q;
  float dd = q - h1[row * 128 + t];
  float ss = dd * dd;
#pragma unroll
  for (int o = 32; o > 0; o >>= 1) ss += __shfl_xor(ss, o);
  __shared__ float p[2];
  if ((t & 63) == 0) p[t >> 6] = ss;
  __syncthreads();
  if (t == 0) atomicAdd(&scal_d[3], (double)(p[0] + p[1]));
}

// sum of squared diff (h1 - quantized_node) -> scal_d[4]
__global__ __launch_bounds__(256) void k_sqdiff(const float4* __restrict__ a, const float4* __restrict__ b,
                                                double* __restrict__ scal_d) {
  int i = blockIdx.x * 256 + threadIdx.x;
  float s = 0.f;
  const int total = N * 32;
  for (; i < total; i += gridDim.x * 256) {
    float4 x = a[i], y = b[i];
    float d0 = x.x - y.x, d1 = x.y - y.y, d2 = x.z - y.z, d3 = x.w - y.w;
    s += d0 * d0 + d1 * d1 + d2 * d2 + d3 * d3;
  }
#pragma unroll
  for (int o = 32; o > 0; o >>= 1) s += __shfl_xor(s, o);
  if ((threadIdx.x & 63) == 0) atomicAdd(&scal_d[4], (double)s);
}

// final scalar combination
__global__ void k_loss(const double* __restrict__ scal_d, const uint32_t* __restrict__ scal_u,
                       float* __restrict__ o_loss) {
  if (threadIdx.x != 0 || blockIdx.x != 0) return;
  double sum = scal_d[0], sq = scal_d[1], es = scal_d[2];
  double mn = (double)funmap(scal_u[0]);
  double mx = (double)funmap(scal_u[1]);
  double U = (double)scal_u[2];
  const double N2 = 67108864.0;  // 8192^2
  double s = 1.0 / (mx - mn);
  // sum over all (i,j) of (adj - (aq-mn)*s)^2, with adj=1 on U unique edge slots
  double mean = (s * s * (sq - 2.0 * mn * sum + mn * mn * N2) - 2.0 * s * (es - mn * U) + U) / N2;
  double edge = sqrt(mean);
  double commit = 0.25 * scal_d[3] / 1048576.0;
  double frec = scal_d[4] / 1048576.0;
  *o_loss = (float)(frec + edge + commit);
}

extern "C" void kernel_launch(void* const* d_in, const int* in_sizes, int n_in,
                              void* d_out, int out_size, void* d_ws, size_t ws_size,
                              hipStream_t stream) {
  (void)in_sizes; (void)n_in; (void)out_size;
  const float* feats = (const float*)d_in[0];
  const int* src = (const int*)d_in[1];
  const int* dst = (const int*)d_in[2];
  const float* W1 = (const float*)d_in[3];
  const float* b1 = (const float*)d_in[4];
  const float* W2 = (const float*)d_in[5];
  const float* b2 = (const float*)d_in[6];
  const float* dec1W = (const float*)d_in[7];
  const float* dec1b = (const float*)d_in[8];
  const float* dec2W = (const float*)d_in[9];
  const float* dec2b = (const float*)d_in[10];
  const float* linW = (const float*)d_in[11];
  const float* linb = (const float*)d_in[12];
  const float* codebook = (const float*)d_in[13];

  float* out = (float*)d_out;
  float* o_h1 = out;                    // [N,128]
  float* o_q = out + 1048576;           // [N,128]
  float* o_h3 = out + 2097152;          // [N,128]
  float* o_out = out + 3145728;         // [N,64]
  float* o_loss = out + 3670016;        // scalar
  float* o_dist = out + 3670017;        // [N,4096] (float-misaligned base!)
  float* o_cn = out + 37224449;         // [C,128]  (float-misaligned base!)

  char* w = (char*)d_ws;
  size_t off = 0;
  auto alloc = [&](size_t b) { char* p = w + off; off = (off + b + 255) & ~(size_t)255; return p; };
  uint32_t* bits = (uint32_t*)alloc(8388608);            // N*N/8 adjacency bitmask
  int* dego = (int*)alloc(N * 4);
  int* degi = (int*)alloc(N * 4);
  unsigned long long* amax = (unsigned long long*)alloc(N * 8);
  double* scal_d = (double*)alloc(256);                  // [0]=sum [1]=sumsq [2]=edge-sum [3]=commit [4]=frec
  uint32_t* scal_u = (uint32_t*)(scal_d + 8);            // [0]=min [1]=max [2]=U
  size_t zero_bytes = off;                               // everything above must start at 0
  int* rowptr = (int*)alloc((N + 1) * 4);
  int* cursor = (int*)alloc(N * 4);
  int* csr = (int*)alloc(E * 4);
  float* nsrc = (float*)alloc(N * 4);
  float* ndst = (float*)alloc(N * 4);
  float* tmp = (float*)alloc((size_t)N * D * 4);
  float* agg = (float*)alloc((size_t)N * D * 4);
  float* xn = (float*)alloc((size_t)N * D * 4);
  float* cnws = (float*)alloc((size_t)C * D * 4);        // aligned copy of cn
  float* qe = (float*)alloc((size_t)N * D * 4);
  float* qn = (float*)alloc((size_t)N * D * 4);
  if (ws_size < off) return;  // insufficient scratch (will fail validation loudly)

  hipMemsetAsync(d_ws, 0, zero_bytes, stream);
  k_init<<<1, 256, 0, stream>>>(scal_u);

  // graph structure
  k_degree<<<E / 256, 256, 0, stream>>>(src, dst, bits, dego, degi, scal_u);
  k_norms<<<N / 256, 256, 0, stream>>>(dego, degi, nsrc, ndst);
  k_scan<<<1, 1024, 0, stream>>>(degi, rowptr, cursor);
  k_scatter<<<E / 256, 256, 0, stream>>>(src, dst, cursor, csr);

  // conv1: h1 = relu((scatter(feats*nsrc)*ndst) @ W1 + b1)
  k_scale<<<N * 32 / 256, 256, 0, stream>>>((const float4*)feats, nsrc, (float4*)tmp);
  k_aggregate<<<N, 128, 0, stream>>>(rowptr, csr, tmp, ndst, agg);
  k_mm<128, true><<<N / 32, 256, 0, stream>>>(agg, W1, b1, o_h1);

  // VQ: cn, xn, dist (+argmax), q, commit loss
  k_l2norm<<<C / 4, 256, 0, stream>>>(codebook, cnws, o_cn, C);
  k_l2norm<<<N / 4, 256, 0, stream>>>(o_h1, xn, nullptr, N);
  k_gemm<false><<<dim3(C / 128, N / 128), 256, 0, stream>>>(xn, cnws, o_dist, amax, nullptr, nullptr, nullptr);
  k_q<<<N, 128, 0, stream>>>(amax, cnws, o_h1, o_q, scal_d);

  // decoders
  k_mm<128, false><<<N / 32, 256, 0, stream>>>(o_q, dec1W, dec1b, qe);
  k_mm<128, false><<<N / 32, 256, 0, stream>>>(o_q, dec2W, dec2b, qn);
  k_sqdiff<<<512, 256, 0, stream>>>((const float4*)o_h1, (const float4*)qn, scal_d);

  // adjacency reconstruction loss (fused reductions, upper-triangle only)
  k_gemm<true><<<dim3(N / 128, N / 128), 256, 0, stream>>>(qe, qe, nullptr, nullptr, bits, scal_d, scal_u);

  // conv2 on quantized_edge + linear head
  k_scale<<<N * 32 / 256, 256, 0, stream>>>((const float4*)qe, nsrc, (float4*)tmp);
  k_aggregate<<<N, 128, 0, stream>>>(rowptr, csr, tmp, ndst, agg);
  k_mm<128, true><<<N / 32, 256, 0, stream>>>(agg, W2, b2, o_h3);
  k_mm<64, false><<<N / 64, 256, 0, stream>>>(o_h3, linW, linb, o_out);

  k_loss<<<1, 64, 0, stream>>>(scal_d, scal_u, o_loss);
}

// Round 5
// 928.526 us; speedup vs baseline: 5.2134x; 1.0346x over previous
//
#include <hip/hip_runtime.h>
#include <cstdint>

// Problem constants
constexpr int N = 8192, E = 262144, D = 128, O = 64, C = 4096;

#define DEV __device__ __forceinline__

typedef short s8v __attribute__((ext_vector_type(8)));   // 8 bf16 (4 VGPRs)
typedef float f4v __attribute__((ext_vector_type(4)));   // MFMA 16x16 accumulator

// orderable-uint mapping for float atomicMin/Max and packed argmax
DEV unsigned fmap(float f) {
  unsigned u = __float_as_uint(f);
  return (u & 0x80000000u) ? ~u : (u | 0x80000000u);
}
DEV float funmap(unsigned u) {
  unsigned b = (u & 0x80000000u) ? (u & 0x7FFFFFFFu) : ~u;
  return __uint_as_float(b);
}
DEV unsigned short f2bf(float f) {  // RNE float->bf16 (finite inputs)
  uint32_t b = __float_as_uint(f);
  return (unsigned short)((b + 0x7FFFu + ((b >> 16) & 1u)) >> 16);
}

// ---------------- setup kernels ----------------

__global__ __launch_bounds__(256) void k_init(uint32_t* scal_u) {
  if (threadIdx.x == 0 && blockIdx.x == 0) scal_u[0] = 0xFFFFFFFFu;  // min slot
}

// degrees + adjacency bitmask + unique-edge count
__global__ __launch_bounds__(256) void k_degree(const int* __restrict__ src, const int* __restrict__ dst,
    uint32_t* __restrict__ bits, int* __restrict__ dego, int* __restrict__ degi,
    uint32_t* __restrict__ scal_u) {
  int e = blockIdx.x * 256 + threadIdx.x;
  int s = src[e], d = dst[e];
  atomicAdd(&dego[s], 1);
  atomicAdd(&degi[d], 1);
  unsigned idx = (unsigned)s * 8192u + (unsigned)d;
  unsigned bit = 1u << (idx & 31);
  unsigned old = atomicOr(&bits[idx >> 5], bit);
  bool isnew = !(old & bit);
  unsigned long long b = __ballot(isnew);
  if ((threadIdx.x & 63) == 0) atomicAdd(&scal_u[2], (unsigned)__popcll(b));
}

__global__ __launch_bounds__(256) void k_norms(const int* __restrict__ dego, const int* __restrict__ degi,
                                               float* __restrict__ nsrc, float* __restrict__ ndst) {
  int i = blockIdx.x * 256 + threadIdx.x;
  if (i >= N) return;
  int a = dego[i], b = degi[i];
  nsrc[i] = a > 0 ? 1.0f / sqrtf((float)a) : 0.0f;
  ndst[i] = b > 0 ? 1.0f / sqrtf((float)b) : 0.0f;
}

// exclusive scan of deg_in -> row_ptr, cursor (single block, 1024 threads, 8 elems each)
__global__ __launch_bounds__(1024) void k_scan(const int* __restrict__ degi, int* __restrict__ rowptr,
                                               int* __restrict__ cursor) {
  __shared__ int sh[1024];
  int tid = threadIdx.x;
  int base = tid * 8;
  int v[8];
  int s = 0;
#pragma unroll
  for (int j = 0; j < 8; ++j) { v[j] = degi[base + j]; s += v[j]; }
  sh[tid] = s;
  __syncthreads();
  for (int off = 1; off < 1024; off <<= 1) {
    int t = (tid >= off) ? sh[tid - off] : 0;
    __syncthreads();
    sh[tid] += t;
    __syncthreads();
  }
  int run = (tid == 0) ? 0 : sh[tid - 1];
#pragma unroll
  for (int j = 0; j < 8; ++j) { rowptr[base + j] = run; cursor[base + j] = run; run += v[j]; }
  if (tid == 1023) rowptr[N] = run;
}

__global__ __launch_bounds__(256) void k_scatter(const int* __restrict__ src, const int* __restrict__ dst,
                                                 int* __restrict__ cursor, int* __restrict__ csr) {
  int e = blockIdx.x * 256 + threadIdx.x;
  int d = dst[e];
  int pos = atomicAdd(&cursor[d], 1);
  csr[pos] = src[e];
}

// out[i,:] = in[i,:] * norm[i]  (float4 over N*32)
__global__ __launch_bounds__(256) void k_scale(const float4* __restrict__ in, const float* __restrict__ norm,
                                               float4* __restrict__ out) {
  int i = blockIdx.x * 256 + threadIdx.x;
  if (i >= N * 32) return;
  float s = norm[i >> 5];
  float4 v = in[i];
  v.x *= s; v.y *= s; v.z *= s; v.w *= s;
  out[i] = v;
}

// fp32 -> bf16 row-major copy (for MFMA adjq input)
__global__ __launch_bounds__(256) void k_tobf16(const float4* __restrict__ in, ushort4* __restrict__ out) {
  int i = blockIdx.x * 256 + threadIdx.x;
  if (i >= N * 32) return;
  float4 v = in[i];
  ushort4 o;
  o.x = f2bf(v.x); o.y = f2bf(v.y); o.z = f2bf(v.z); o.w = f2bf(v.w);
  out[i] = o;
}

// CSR gather-aggregate: out[row,:] = (sum over in-edges of tmp[src,:]) * ndst[row]
__global__ __launch_bounds__(128) void k_aggregate(const int* __restrict__ rowptr, const int* __restrict__ csr,
    const float* __restrict__ tmp, const float* __restrict__ ndst, float* __restrict__ out) {
  int row = blockIdx.x, t = threadIdx.x;
  int e0 = rowptr[row], e1 = rowptr[row + 1];
  float acc = 0.f;
  int e = e0;
  for (; e + 4 <= e1; e += 4) {
    int s0 = csr[e], s1 = csr[e + 1], s2 = csr[e + 2], s3 = csr[e + 3];
    acc += tmp[s0 * 128 + t];
    acc += tmp[s1 * 128 + t];
    acc += tmp[s2 * 128 + t];
    acc += tmp[s3 * 128 + t];
  }
  for (; e < e1; ++e) acc += tmp[csr[e] * 128 + t];
  out[row * 128 + t] = acc * ndst[row];
}

// row-wise l2 normalize (one wave per row). out_extra: optional scalar-store copy (misaligned base ok)
__global__ __launch_bounds__(256) void k_l2norm(const float* __restrict__ in, float* __restrict__ out_al,
                                                float* __restrict__ out_extra, int rows) {
  int wave = threadIdx.x >> 6, lane = threadIdx.x & 63;
  int row = blockIdx.x * 4 + wave;
  if (row >= rows) return;
  float2 v = ((const float2*)in)[row * 64 + lane];
  float ss = v.x * v.x + v.y * v.y;
#pragma unroll
  for (int o = 32; o > 0; o >>= 1) ss += __shfl_xor(ss, o);
  float den = fmaxf(sqrtf(ss), 1e-12f);
  float ox = v.x / den, oy = v.y / den;
  ((float2*)out_al)[row * 64 + lane] = make_float2(ox, oy);
  if (out_extra != nullptr) {
    out_extra[row * 128 + 2 * lane] = ox;
    out_extra[row * 128 + 2 * lane + 1] = oy;
  }
}

// ---------------- small matmul: out[M,CO] = A[M,128] @ W[128,CO] + bias (+relu) ----------------
template <int CO, bool RELU>
__global__ __launch_bounds__(256, 2) void k_mm(const float* __restrict__ A, const float* __restrict__ W,
    const float* __restrict__ bias, float* __restrict__ out) {
  constexpr int CG = CO / 4;       // col f4 groups
  constexpr int RG = 256 / CG;     // row groups
  constexpr int TR = RG * 4;       // tile rows (CO=128 -> 32, CO=64 -> 64)
  constexpr int WIT = (64 * CG) / 256;
  __shared__ __align__(16) float Al[TR * 128];
  __shared__ __align__(16) float Wl[64 * CO];
  int tid = threadIdx.x;
  int cg = tid % CG, rg = tid / CG;
  int rbase = blockIdx.x * TR;
#pragma unroll
  for (int it = 0; it < TR / 8; ++it) {
    int idx = tid + it * 256;
    int r = idx >> 5, c = idx & 31;
    *(float4*)&Al[r * 128 + c * 4] = *(const float4*)&A[(rbase + r) * 128 + c * 4];
  }
  float acc[4][4] = {};
  for (int kc = 0; kc < 128; kc += 64) {
    __syncthreads();
#pragma unroll
    for (int it = 0; it < WIT; ++it) {
      int idx = tid + it * 256;
      int r = idx / CG, c = idx % CG;
      *(float4*)&Wl[r * CO + c * 4] = *(const float4*)&W[(kc + r) * CO + c * 4];
    }
    __syncthreads();
#pragma unroll
    for (int k = 0; k < 64; ++k) {
      float4 w4 = *(const float4*)&Wl[k * CO + cg * 4];
#pragma unroll
      for (int i = 0; i < 4; ++i) {
        float a = Al[(rg * 4 + i) * 128 + kc + k];
        acc[i][0] += a * w4.x; acc[i][1] += a * w4.y; acc[i][2] += a * w4.z; acc[i][3] += a * w4.w;
      }
    }
  }
  float4 b4 = *(const float4*)&bias[cg * 4];
#pragma unroll
  for (int i = 0; i < 4; ++i) {
    float4 o;
    o.x = acc[i][0] + b4.x; o.y = acc[i][1] + b4.y; o.z = acc[i][2] + b4.z; o.w = acc[i][3] + b4.w;
    if (RELU) { o.x = fmaxf(o.x, 0.f); o.y = fmaxf(o.y, 0.f); o.z = fmaxf(o.z, 0.f); o.w = fmaxf(o.w, 0.f); }
    *(float4*)&out[(rbase + rg * 4 + i) * CO + cg * 4] = o;
  }
}

// ---------------- dist NT GEMM (fp32, exact argmax): dist = xn @ cn^T ----------------
// 128x128 tile, BK=32 (LDS 36 KB -> 4 blocks/CU), 8x8 micro-tile, fused row argmax.
// Row stride 36 dwords (=4 mod 32) staggers rows across banks: stores & reads 2 lanes/bank (free).
// unroll 1 on k4 keeps live set ~115 VGPRs (see round-3/4 notes: unrolling spilled at 256).
__global__ __launch_bounds__(256) void k_gemm(const float* __restrict__ A, const float* __restrict__ B,
    float* __restrict__ dout, unsigned long long* __restrict__ amax) {
  int bx = blockIdx.x, by = blockIdx.y;
  int rbase = by * 128, cbase = bx * 128;
  __shared__ __align__(16) float Al[128 * 36];
  __shared__ __align__(16) float Bl[128 * 36];
  int tid = threadIdx.x;
  int tx = tid & 15, ty = tid >> 4;
  float acc[8][8];
#pragma unroll
  for (int i = 0; i < 8; ++i)
#pragma unroll
    for (int j = 0; j < 8; ++j) acc[i][j] = 0.f;

  for (int kc = 0; kc < 128; kc += 32) {
#pragma unroll
    for (int it = 0; it < 4; ++it) {
      int idx = tid + it * 256;
      int r = idx >> 3, c = idx & 7;
      *(float4*)&Al[r * 36 + c * 4] = *(const float4*)&A[(rbase + r) * 128 + kc + c * 4];
      *(float4*)&Bl[r * 36 + c * 4] = *(const float4*)&B[(cbase + r) * 128 + kc + c * 4];
    }
    __syncthreads();
#pragma unroll 1   // keep live set small: no cross-iteration pipelining (round-3 spill lesson)
    for (int k4 = 0; k4 < 8; ++k4) {
      float4 a[8];
#pragma unroll
      for (int i = 0; i < 8; ++i) a[i] = *(const float4*)&Al[(ty + (i << 4)) * 36 + (k4 << 2)];
#pragma unroll
      for (int j = 0; j < 8; ++j) {
        float4 b = *(const float4*)&Bl[(tx + (j << 4)) * 36 + (k4 << 2)];
#pragma unroll
        for (int i = 0; i < 8; ++i)
          acc[i][j] += a[i].x * b.x + a[i].y * b.y + a[i].z * b.z + a[i].w * b.w;
      }
    }
    __syncthreads();
  }

  float bestv[8];
  int bestc[8];
#pragma unroll
  for (int i = 0; i < 8; ++i) { bestv[i] = -3.4e38f; bestc[i] = 0; }
#pragma unroll
  for (int i = 0; i < 8; ++i) {
    int row = rbase + ty + (i << 4);
#pragma unroll
    for (int j = 0; j < 8; ++j) {
      int col = cbase + tx + (j << 4);
      float v = acc[i][j];
      dout[row * 4096 + col] = v;   // scalar store: dist base is float-misaligned for float4
      if (v > bestv[i]) { bestv[i] = v; bestc[i] = col; }  // strict > keeps lowest col (np tie rule)
    }
  }
  unsigned long long* sc = (unsigned long long*)Al;  // 16 KB <= 18 KB, past last barrier
#pragma unroll
  for (int i = 0; i < 8; ++i)
    sc[(ty + (i << 4)) * 16 + tx] =
        (((unsigned long long)fmap(bestv[i])) << 32) | (unsigned long long)(0xFFFFFFFFu - (unsigned)bestc[i]);
  __syncthreads();
  if (tid < 128) {
    unsigned long long m = 0ull;
#pragma unroll
    for (int k = 0; k < 16; ++k) {
      unsigned long long t = sc[tid * 16 + k];
      m = t > m ? t : m;
    }
    atomicMax(&amax[rbase + tid], m);
  }
}

// ---------------- adjq via bf16 MFMA: fused loss reductions over qe @ qe^T ----------------
// Upper-triangle 128x128 blocks; 4 waves, each wave = 32 rows x 128 cols of 16x16x32 tiles.
// Verified gfx950 layouts (guide m89/m91/m120): C/D col=lane&15,row=quad*4+reg;
// A/B frag [idx=lane&15][k=quad*8+j], row-major NT inputs. acc fp32; loss error ~5e-4.
__global__ __launch_bounds__(256) void k_adjq(const unsigned short* __restrict__ qb,
    const uint32_t* __restrict__ bits, double* __restrict__ scal_d, uint32_t* __restrict__ scal_u) {
  int bx = blockIdx.x, by = blockIdx.y;
  if (bx < by) return;
  int rbase = by * 128, cbase = bx * 128;
  __shared__ unsigned short Ab[128 * 132];  // +4 bf16 pad: stride 66 dwords -> 2 lanes/bank
  __shared__ unsigned short Bb[128 * 132];
  int tid = threadIdx.x;
#pragma unroll
  for (int it = 0; it < 8; ++it) {
    int idx = tid + it * 256;     // 128 rows x 16 chunks of 8 bf16
    int r = idx >> 4, ch = idx & 15;
    *(s8v*)&Ab[r * 132 + ch * 8] = *(const s8v*)&qb[(rbase + r) * 128 + ch * 8];
    *(s8v*)&Bb[r * 132 + ch * 8] = *(const s8v*)&qb[(cbase + r) * 128 + ch * 8];
  }
  __syncthreads();
  int wave = tid >> 6, lane = tid & 63;
  int l15 = lane & 15, quad = lane >> 4;
  int wr = wave * 32;
  f4v acc[2][8];
#pragma unroll
  for (int rt = 0; rt < 2; ++rt)
#pragma unroll
    for (int ct = 0; ct < 8; ++ct) acc[rt][ct] = {0.f, 0.f, 0.f, 0.f};
  s8v a[2][4];
#pragma unroll
  for (int rt = 0; rt < 2; ++rt)
#pragma unroll
    for (int kq = 0; kq < 4; ++kq)
      a[rt][kq] = *(const s8v*)&Ab[(wr + rt * 16 + l15) * 132 + kq * 32 + quad * 8];
#pragma unroll
  for (int ct = 0; ct < 8; ++ct) {
    s8v b[4];
#pragma unroll
    for (int kq = 0; kq < 4; ++kq)
      b[kq] = *(const s8v*)&Bb[(ct * 16 + l15) * 132 + kq * 32 + quad * 8];
#pragma unroll
    for (int rt = 0; rt < 2; ++rt)
#pragma unroll
      for (int kq = 0; kq < 4; ++kq)
        acc[rt][ct] = __builtin_amdgcn_mfma_f32_16x16x32_bf16(a[rt][kq], b[kq], acc[rt][ct], 0, 0, 0);
  }
  __syncthreads();
  // stage adjacency bit tiles (both orientations) into LDS (reuse Ab)
  uint32_t* bl = (uint32_t*)Ab;   // bl[lr*4+w]: bits(row=rbase+lr, cols cbase..+127)
  uint32_t* blT = bl + 512;       // blT[lc*4+w]: bits(row=cbase+lc, cols rbase..+127)
#pragma unroll
  for (int it = 0; it < 2; ++it) {
    int idx = tid + it * 256;
    int r = idx >> 2, wq = idx & 3;
    bl[idx] = bits[(rbase + r) * 256 + (cbase >> 5) + wq];
    blT[idx] = bits[(cbase + r) * 256 + (rbase >> 5) + wq];
  }
  __syncthreads();
  float lsum = 0.f, lsq = 0.f, les = 0.f;
  float lmin = 3.4e38f, lmax = -3.4e38f;
  bool diag = (bx == by);
#pragma unroll
  for (int rt = 0; rt < 2; ++rt)
#pragma unroll
    for (int ct = 0; ct < 8; ++ct)
#pragma unroll
      for (int reg = 0; reg < 4; ++reg) {
        int lr = wr + rt * 16 + quad * 4 + reg;
        int lc = ct * 16 + l15;
        if (diag && lc < lr) continue;          // upper triangle incl. diagonal
        float v = acc[rt][ct][reg];
        bool ondiag = diag && (lc == lr);
        float wgt = ondiag ? 1.f : 2.f;
        lsum += wgt * v;
        lsq += wgt * v * v;
        lmin = fminf(lmin, v);
        lmax = fmaxf(lmax, v);
        unsigned eb = (bl[lr * 4 + (lc >> 5)] >> (lc & 31)) & 1u;
        if (!ondiag) eb += (blT[lc * 4 + (lr >> 5)] >> (lr & 31)) & 1u;
        if (eb) les += (float)eb * v;
      }
  double dsum = (double)lsum, dsq = (double)lsq, des = (double)les;
#pragma unroll
  for (int o = 32; o > 0; o >>= 1) {
    dsum += __shfl_xor(dsum, o);
    dsq += __shfl_xor(dsq, o);
    des += __shfl_xor(des, o);
    lmin = fminf(lmin, __shfl_xor(lmin, o));
    lmax = fmaxf(lmax, __shfl_xor(lmax, o));
  }
  if (lane == 0) {
    atomicAdd(&scal_d[0], dsum);
    atomicAdd(&scal_d[1], dsq);
    atomicAdd(&scal_d[2], des);
    atomicMin(&scal_u[0], fmap(lmin));
    atomicMax(&scal_u[1], fmap(lmax));
  }
}

// gather chosen codes -> quantized output; accumulate commit loss sum
__global__ __launch_bounds__(128) void k_q(const unsigned long long* __restrict__ amax,
    const float* __restrict__ cnws, const float* __restrict__ h1, float* __restrict__ qout,
    double* __restrict__ scal_d) {
  int row = blockIdx.x, t = threadIdx.x;
  unsigned long long key = amax[row];
  int col = (int)(0xFFFFFFFFu - (uint32_t)(key & 0xFFFFFFFFull));
  float q = cnws[col * 128 + t];
  qout[row * 128 + t] = q;
  float dd = q - h1[row * 128 + t];
  float ss = dd * dd;
#pragma unroll
  for (int o = 32; o > 0; o >>= 1) ss += __shfl_xor(ss, o);
  __shared__ float p[2];
  if ((t & 63) == 0) p[t >> 6] = ss;
  __syncthreads();
  if (t == 0) atomicAdd(&scal_d[3], (double)(p[0] + p[1]));
}

// sum of squared diff (h1 - quantized_node) -> scal_d[4]
__global__ __launch_bounds__(256) void k_sqdiff(const float4* __restrict__ a, const float4* __restrict__ b,
                                                double* __restrict__ scal_d) {
  int i = blockIdx.x * 256 + threadIdx.x;
  float s = 0.f;
  const int total = N * 32;
  for (; i < total; i += gridDim.x * 256) {
    float4 x = a[i], y = b[i];
    float d0 = x.x - y.x, d1 = x.y - y.y, d2 = x.z - y.z, d3 = x.w - y.w;
    s += d0 * d0 + d1 * d1 + d2 * d2 + d3 * d3;
  }
#pragma unroll
  for (int o = 32; o > 0; o >>= 1) s += __shfl_xor(s, o);
  if ((threadIdx.x & 63) == 0) atomicAdd(&scal_d[4], (double)s);
}

// final scalar combination
__global__ void k_loss(const double* __restrict__ scal_d, const uint32_t* __restrict__ scal_u,
                       float* __restrict__ o_loss) {
  if (threadIdx.x != 0 || blockIdx.x != 0) return;
  double sum = scal_d[0], sq = scal_d[1], es = scal_d[2];
  double mn = (double)funmap(scal_u[0]);
  double mx = (double)funmap(scal_u[1]);
  double U = (double)scal_u[2];
  const double N2 = 67108864.0;  // 8192^2
  double s = 1.0 / (mx - mn);
  // sum over all (i,j) of (adj - (aq-mn)*s)^2, with adj=1 on U unique edge slots
  double mean = (s * s * (sq - 2.0 * mn * sum + mn * mn * N2) - 2.0 * s * (es - mn * U) + U) / N2;
  double edge = sqrt(mean);
  double commit = 0.25 * scal_d[3] / 1048576.0;
  double frec = scal_d[4] / 1048576.0;
  *o_loss = (float)(frec + edge + commit);
}

extern "C" void kernel_launch(void* const* d_in, const int* in_sizes, int n_in,
                              void* d_out, int out_size, void* d_ws, size_t ws_size,
                              hipStream_t stream) {
  (void)in_sizes; (void)n_in; (void)out_size;
  const float* feats = (const float*)d_in[0];
  const int* src = (const int*)d_in[1];
  const int* dst = (const int*)d_in[2];
  const float* W1 = (const float*)d_in[3];
  const float* b1 = (const float*)d_in[4];
  const float* W2 = (const float*)d_in[5];
  const float* b2 = (const float*)d_in[6];
  const float* dec1W = (const float*)d_in[7];
  const float* dec1b = (const float*)d_in[8];
  const float* dec2W = (const float*)d_in[9];
  const float* dec2b = (const float*)d_in[10];
  const float* linW = (const float*)d_in[11];
  const float* linb = (const float*)d_in[12];
  const float* codebook = (const float*)d_in[13];

  float* out = (float*)d_out;
  float* o_h1 = out;                    // [N,128]
  float* o_q = out + 1048576;           // [N,128]
  float* o_h3 = out + 2097152;          // [N,128]
  float* o_out = out + 3145728;         // [N,64]
  float* o_loss = out + 3670016;        // scalar
  float* o_dist = out + 3670017;        // [N,4096] (float-misaligned base!)
  float* o_cn = out + 37224449;         // [C,128]  (float-misaligned base!)

  char* w = (char*)d_ws;
  size_t off = 0;
  auto alloc = [&](size_t b) { char* p = w + off; off = (off + b + 255) & ~(size_t)255; return p; };
  uint32_t* bits = (uint32_t*)alloc(8388608);            // N*N/8 adjacency bitmask
  int* dego = (int*)alloc(N * 4);
  int* degi = (int*)alloc(N * 4);
  unsigned long long* amax = (unsigned long long*)alloc(N * 8);
  double* scal_d = (double*)alloc(256);                  // [0]=sum [1]=sumsq [2]=edge-sum [3]=commit [4]=frec
  uint32_t* scal_u = (uint32_t*)(scal_d + 8);            // [0]=min [1]=max [2]=U
  size_t zero_bytes = off;                               // everything above must start at 0
  int* rowptr = (int*)alloc((N + 1) * 4);
  int* cursor = (int*)alloc(N * 4);
  int* csr = (int*)alloc(E * 4);
  float* nsrc = (float*)alloc(N * 4);
  float* ndst = (float*)alloc(N * 4);
  float* tmp = (float*)alloc((size_t)N * D * 4);
  float* agg = (float*)alloc((size_t)N * D * 4);
  float* xn = (float*)alloc((size_t)N * D * 4);
  float* cnws = (float*)alloc((size_t)C * D * 4);        // aligned copy of cn
  float* qe = (float*)alloc((size_t)N * D * 4);
  float* qn = (float*)alloc((size_t)N * D * 4);
  // qb (bf16 copy of qe) aliases tmp: tmp's live ranges are conv1 (before) and conv2
  // (after k_adjq) — stream order makes the overlap safe, saves 2 MB of ws.
  unsigned short* qb = (unsigned short*)tmp;
  if (ws_size < off) return;  // insufficient scratch (will fail validation loudly)

  hipMemsetAsync(d_ws, 0, zero_bytes, stream);
  k_init<<<1, 256, 0, stream>>>(scal_u);

  // graph structure
  k_degree<<<E / 256, 256, 0, stream>>>(src, dst, bits, dego, degi, scal_u);
  k_norms<<<N / 256, 256, 0, stream>>>(dego, degi, nsrc, ndst);
  k_scan<<<1, 1024, 0, stream>>>(degi, rowptr, cursor);
  k_scatter<<<E / 256, 256, 0, stream>>>(src, dst, cursor, csr);

  // conv1: h1 = relu((scatter(feats*nsrc)*ndst) @ W1 + b1)
  k_scale<<<N * 32 / 256, 256, 0, stream>>>((const float4*)feats, nsrc, (float4*)tmp);
  k_aggregate<<<N, 128, 0, stream>>>(rowptr, csr, tmp, ndst, agg);
  k_mm<128, true><<<N / 32, 256, 0, stream>>>(agg, W1, b1, o_h1);

  // VQ: cn, xn, dist (+argmax), q, commit loss
  k_l2norm<<<C / 4, 256, 0, stream>>>(codebook, cnws, o_cn, C);
  k_l2norm<<<N / 4, 256, 0, stream>>>(o_h1, xn, nullptr, N);
  k_gemm<<<dim3(C / 128, N / 128), 256, 0, stream>>>(xn, cnws, o_dist, amax);
  k_q<<<N, 128, 0, stream>>>(amax, cnws, o_h1, o_q, scal_d);

  // decoders
  k_mm<128, false><<<N / 32, 256, 0, stream>>>(o_q, dec1W, dec1b, qe);
  k_mm<128, false><<<N / 32, 256, 0, stream>>>(o_q, dec2W, dec2b, qn);
  k_sqdiff<<<512, 256, 0, stream>>>((const float4*)o_h1, (const float4*)qn, scal_d);

  // adjacency reconstruction loss: bf16 MFMA over upper-triangle blocks
  k_tobf16<<<N * 32 / 256, 256, 0, stream>>>((const float4*)qe, (ushort4*)qb);
  k_adjq<<<dim3(N / 128, N / 128), 256, 0, stream>>>(qb, bits, scal_d, scal_u);

  // conv2 on quantized_edge + linear head
  k_scale<<<N * 32 / 256, 256, 0, stream>>>((const float4*)qe, nsrc, (float4*)tmp);
  k_aggregate<<<N, 128, 0, stream>>>(rowptr, csr, tmp, ndst, agg);
  k_mm<128, true><<<N / 32, 256, 0, stream>>>(agg, W2, b2, o_h3);
  k_mm<64, false><<<N / 64, 256, 0, stream>>>(o_h3, linW, linb, o_out);

  k_loss<<<1, 64, 0, stream>>>(scal_d, scal_u, o_loss);
}

// Round 6
// 550.051 us; speedup vs baseline: 8.8007x; 1.6881x over previous
//
#include <hip/hip_runtime.h>
#include <cstdint>

// Problem constants
constexpr int N = 8192, E = 262144, D = 128, O = 64, C = 4096;

#define DEV __device__ __forceinline__

typedef short s8v __attribute__((ext_vector_type(8)));   // 8 bf16 (4 VGPRs)
typedef float f4v __attribute__((ext_vector_type(4)));   // MFMA 16x16 accumulator

// orderable-uint mapping for float packed argmax
DEV unsigned fmap(float f) {
  unsigned u = __float_as_uint(f);
  return (u & 0x80000000u) ? ~u : (u | 0x80000000u);
}
DEV unsigned short f2bf(float f) {  // RNE float->bf16 (finite inputs)
  uint32_t b = __float_as_uint(f);
  return (unsigned short)((b + 0x7FFFu + ((b >> 16) & 1u)) >> 16);
}

// ---------------- setup kernels ----------------

// degrees + adjacency bitmask + unique-edge count (integer atomics only: native, uncontended-ish)
__global__ __launch_bounds__(256) void k_degree(const int* __restrict__ src, const int* __restrict__ dst,
    uint32_t* __restrict__ bits, int* __restrict__ dego, int* __restrict__ degi,
    uint32_t* __restrict__ scal_u) {
  int e = blockIdx.x * 256 + threadIdx.x;
  int s = src[e], d = dst[e];
  atomicAdd(&dego[s], 1);
  atomicAdd(&degi[d], 1);
  unsigned idx = (unsigned)s * 8192u + (unsigned)d;
  unsigned bit = 1u << (idx & 31);
  unsigned old = atomicOr(&bits[idx >> 5], bit);
  bool isnew = !(old & bit);
  unsigned long long b = __ballot(isnew);
  if ((threadIdx.x & 63) == 0) atomicAdd(&scal_u[2], (unsigned)__popcll(b));
}

__global__ __launch_bounds__(256) void k_norms(const int* __restrict__ dego, const int* __restrict__ degi,
                                               float* __restrict__ nsrc, float* __restrict__ ndst) {
  int i = blockIdx.x * 256 + threadIdx.x;
  if (i >= N) return;
  int a = dego[i], b = degi[i];
  nsrc[i] = a > 0 ? 1.0f / sqrtf((float)a) : 0.0f;
  ndst[i] = b > 0 ? 1.0f / sqrtf((float)b) : 0.0f;
}

// exclusive scan of deg_in -> row_ptr, cursor (single block, 1024 threads, 8 elems each)
__global__ __launch_bounds__(1024) void k_scan(const int* __restrict__ degi, int* __restrict__ rowptr,
                                               int* __restrict__ cursor) {
  __shared__ int sh[1024];
  int tid = threadIdx.x;
  int base = tid * 8;
  int v[8];
  int s = 0;
#pragma unroll
  for (int j = 0; j < 8; ++j) { v[j] = degi[base + j]; s += v[j]; }
  sh[tid] = s;
  __syncthreads();
  for (int off = 1; off < 1024; off <<= 1) {
    int t = (tid >= off) ? sh[tid - off] : 0;
    __syncthreads();
    sh[tid] += t;
    __syncthreads();
  }
  int run = (tid == 0) ? 0 : sh[tid - 1];
#pragma unroll
  for (int j = 0; j < 8; ++j) { rowptr[base + j] = run; cursor[base + j] = run; run += v[j]; }
  if (tid == 1023) rowptr[N] = run;
}

__global__ __launch_bounds__(256) void k_scatter(const int* __restrict__ src, const int* __restrict__ dst,
                                                 int* __restrict__ cursor, int* __restrict__ csr) {
  int e = blockIdx.x * 256 + threadIdx.x;
  int d = dst[e];
  int pos = atomicAdd(&cursor[d], 1);
  csr[pos] = src[e];
}

// out[i,:] = in[i,:] * norm[i]  (float4 over N*32)
__global__ __launch_bounds__(256) void k_scale(const float4* __restrict__ in, const float* __restrict__ norm,
                                               float4* __restrict__ out) {
  int i = blockIdx.x * 256 + threadIdx.x;
  if (i >= N * 32) return;
  float s = norm[i >> 5];
  float4 v = in[i];
  v.x *= s; v.y *= s; v.z *= s; v.w *= s;
  out[i] = v;
}

// fp32 -> bf16 row-major copy (for MFMA adjq input)
__global__ __launch_bounds__(256) void k_tobf16(const float4* __restrict__ in, ushort4* __restrict__ out) {
  int i = blockIdx.x * 256 + threadIdx.x;
  if (i >= N * 32) return;
  float4 v = in[i];
  ushort4 o;
  o.x = f2bf(v.x); o.y = f2bf(v.y); o.z = f2bf(v.z); o.w = f2bf(v.w);
  out[i] = o;
}

// CSR gather-aggregate: out[row,:] = (sum over in-edges of tmp[src,:]) * ndst[row]
__global__ __launch_bounds__(128) void k_aggregate(const int* __restrict__ rowptr, const int* __restrict__ csr,
    const float* __restrict__ tmp, const float* __restrict__ ndst, float* __restrict__ out) {
  int row = blockIdx.x, t = threadIdx.x;
  int e0 = rowptr[row], e1 = rowptr[row + 1];
  float acc = 0.f;
  int e = e0;
  for (; e + 4 <= e1; e += 4) {
    int s0 = csr[e], s1 = csr[e + 1], s2 = csr[e + 2], s3 = csr[e + 3];
    acc += tmp[s0 * 128 + t];
    acc += tmp[s1 * 128 + t];
    acc += tmp[s2 * 128 + t];
    acc += tmp[s3 * 128 + t];
  }
  for (; e < e1; ++e) acc += tmp[csr[e] * 128 + t];
  out[row * 128 + t] = acc * ndst[row];
}

// row-wise l2 normalize (one wave per row). out_extra: optional scalar-store copy (misaligned base ok)
__global__ __launch_bounds__(256) void k_l2norm(const float* __restrict__ in, float* __restrict__ out_al,
                                                float* __restrict__ out_extra, int rows) {
  int wave = threadIdx.x >> 6, lane = threadIdx.x & 63;
  int row = blockIdx.x * 4 + wave;
  if (row >= rows) return;
  float2 v = ((const float2*)in)[row * 64 + lane];
  float ss = v.x * v.x + v.y * v.y;
#pragma unroll
  for (int o = 32; o > 0; o >>= 1) ss += __shfl_xor(ss, o);
  float den = fmaxf(sqrtf(ss), 1e-12f);
  float ox = v.x / den, oy = v.y / den;
  ((float2*)out_al)[row * 64 + lane] = make_float2(ox, oy);
  if (out_extra != nullptr) {
    out_extra[row * 128 + 2 * lane] = ox;
    out_extra[row * 128 + 2 * lane + 1] = oy;
  }
}

// ---------------- small matmul: out[M,CO] = A[M,128] @ W[128,CO] + bias (+relu) ----------------
template <int CO, bool RELU>
__global__ __launch_bounds__(256, 2) void k_mm(const float* __restrict__ A, const float* __restrict__ W,
    const float* __restrict__ bias, float* __restrict__ out) {
  constexpr int CG = CO / 4;       // col f4 groups
  constexpr int RG = 256 / CG;     // row groups
  constexpr int TR = RG * 4;       // tile rows (CO=128 -> 32, CO=64 -> 64)
  constexpr int WIT = (64 * CG) / 256;
  __shared__ __align__(16) float Al[TR * 128];
  __shared__ __align__(16) float Wl[64 * CO];
  int tid = threadIdx.x;
  int cg = tid % CG, rg = tid / CG;
  int rbase = blockIdx.x * TR;
#pragma unroll
  for (int it = 0; it < TR / 8; ++it) {
    int idx = tid + it * 256;
    int r = idx >> 5, c = idx & 31;
    *(float4*)&Al[r * 128 + c * 4] = *(const float4*)&A[(rbase + r) * 128 + c * 4];
  }
  float acc[4][4] = {};
  for (int kc = 0; kc < 128; kc += 64) {
    __syncthreads();
#pragma unroll
    for (int it = 0; it < WIT; ++it) {
      int idx = tid + it * 256;
      int r = idx / CG, c = idx % CG;
      *(float4*)&Wl[r * CO + c * 4] = *(const float4*)&W[(kc + r) * CO + c * 4];
    }
    __syncthreads();
#pragma unroll
    for (int k = 0; k < 64; ++k) {
      float4 w4 = *(const float4*)&Wl[k * CO + cg * 4];
#pragma unroll
      for (int i = 0; i < 4; ++i) {
        float a = Al[(rg * 4 + i) * 128 + kc + k];
        acc[i][0] += a * w4.x; acc[i][1] += a * w4.y; acc[i][2] += a * w4.z; acc[i][3] += a * w4.w;
      }
    }
  }
  float4 b4 = *(const float4*)&bias[cg * 4];
#pragma unroll
  for (int i = 0; i < 4; ++i) {
    float4 o;
    o.x = acc[i][0] + b4.x; o.y = acc[i][1] + b4.y; o.z = acc[i][2] + b4.z; o.w = acc[i][3] + b4.w;
    if (RELU) { o.x = fmaxf(o.x, 0.f); o.y = fmaxf(o.y, 0.f); o.z = fmaxf(o.z, 0.f); o.w = fmaxf(o.w, 0.f); }
    *(float4*)&out[(rbase + rg * 4 + i) * CO + cg * 4] = o;
  }
}

// ---------------- dist NT GEMM (fp32, exact argmax): dist = xn @ cn^T ----------------
// 128x128 tile, BK=32 (LDS 36 KB -> 4 blocks/CU), 8x8 micro-tile, fused row argmax.
// amax atomicMax is NATIVE u64 integer, scattered over 8192 addresses -> fine.
__global__ __launch_bounds__(256) void k_gemm(const float* __restrict__ A, const float* __restrict__ B,
    float* __restrict__ dout, unsigned long long* __restrict__ amax) {
  int bx = blockIdx.x, by = blockIdx.y;
  int rbase = by * 128, cbase = bx * 128;
  __shared__ __align__(16) float Al[128 * 36];
  __shared__ __align__(16) float Bl[128 * 36];
  int tid = threadIdx.x;
  int tx = tid & 15, ty = tid >> 4;
  float acc[8][8];
#pragma unroll
  for (int i = 0; i < 8; ++i)
#pragma unroll
    for (int j = 0; j < 8; ++j) acc[i][j] = 0.f;

  for (int kc = 0; kc < 128; kc += 32) {
#pragma unroll
    for (int it = 0; it < 4; ++it) {
      int idx = tid + it * 256;
      int r = idx >> 3, c = idx & 7;
      *(float4*)&Al[r * 36 + c * 4] = *(const float4*)&A[(rbase + r) * 128 + kc + c * 4];
      *(float4*)&Bl[r * 36 + c * 4] = *(const float4*)&B[(cbase + r) * 128 + kc + c * 4];
    }
    __syncthreads();
#pragma unroll 1   // keep live set small: no cross-iteration pipelining (round-3 spill lesson)
    for (int k4 = 0; k4 < 8; ++k4) {
      float4 a[8];
#pragma unroll
      for (int i = 0; i < 8; ++i) a[i] = *(const float4*)&Al[(ty + (i << 4)) * 36 + (k4 << 2)];
#pragma unroll
      for (int j = 0; j < 8; ++j) {
        float4 b = *(const float4*)&Bl[(tx + (j << 4)) * 36 + (k4 << 2)];
#pragma unroll
        for (int i = 0; i < 8; ++i)
          acc[i][j] += a[i].x * b.x + a[i].y * b.y + a[i].z * b.z + a[i].w * b.w;
      }
    }
    __syncthreads();
  }

  float bestv[8];
  int bestc[8];
#pragma unroll
  for (int i = 0; i < 8; ++i) { bestv[i] = -3.4e38f; bestc[i] = 0; }
#pragma unroll
  for (int i = 0; i < 8; ++i) {
    int row = rbase + ty + (i << 4);
#pragma unroll
    for (int j = 0; j < 8; ++j) {
      int col = cbase + tx + (j << 4);
      float v = acc[i][j];
      dout[row * 4096 + col] = v;   // scalar store: dist base is float-misaligned for float4
      if (v > bestv[i]) { bestv[i] = v; bestc[i] = col; }  // strict > keeps lowest col (np tie rule)
    }
  }
  unsigned long long* sc = (unsigned long long*)Al;  // 16 KB <= 18 KB, past last barrier
#pragma unroll
  for (int i = 0; i < 8; ++i)
    sc[(ty + (i << 4)) * 16 + tx] =
        (((unsigned long long)fmap(bestv[i])) << 32) | (unsigned long long)(0xFFFFFFFFu - (unsigned)bestc[i]);
  __syncthreads();
  if (tid < 128) {
    unsigned long long m = 0ull;
#pragma unroll
    for (int k = 0; k < 16; ++k) {
      unsigned long long t = sc[tid * 16 + k];
      m = t > m ? t : m;
    }
    atomicMax(&amax[rbase + tid], m);
  }
}

// ---------------- adjq via bf16 MFMA: fused loss reductions over qe @ qe^T ----------------
// Round-5 post-mortem: atomicAdd(double) compiles to a global CAS retry loop; 8320 waves
// spinning on ONE cache line ate 330 µs (MfmaUtil 1% == pure-MFMA time / dur). Fix: write
// per-block partials (early-exit blocks write identities), reduce in k_finish. NO fp atomics.
__global__ __launch_bounds__(256) void k_adjq(const unsigned short* __restrict__ qb,
    const uint32_t* __restrict__ bits,
    double* __restrict__ p_sum, double* __restrict__ p_sq, double* __restrict__ p_es,
    float* __restrict__ p_mn, float* __restrict__ p_mx) {
  int bx = blockIdx.x, by = blockIdx.y;
  int pid = by * gridDim.x + bx;
  int tid = threadIdx.x;
  if (bx < by) {
    if (tid == 0) {
      p_sum[pid] = 0.0; p_sq[pid] = 0.0; p_es[pid] = 0.0;
      p_mn[pid] = 3.4e38f; p_mx[pid] = -3.4e38f;
    }
    return;
  }
  int rbase = by * 128, cbase = bx * 128;
  __shared__ unsigned short Ab[128 * 132];  // +4 bf16 pad: stride 66 dwords -> 2 lanes/bank
  __shared__ unsigned short Bb[128 * 132];
#pragma unroll
  for (int it = 0; it < 8; ++it) {
    int idx = tid + it * 256;     // 128 rows x 16 chunks of 8 bf16
    int r = idx >> 4, ch = idx & 15;
    *(s8v*)&Ab[r * 132 + ch * 8] = *(const s8v*)&qb[(rbase + r) * 128 + ch * 8];
    *(s8v*)&Bb[r * 132 + ch * 8] = *(const s8v*)&qb[(cbase + r) * 128 + ch * 8];
  }
  __syncthreads();
  int wave = tid >> 6, lane = tid & 63;
  int l15 = lane & 15, quad = lane >> 4;
  int wr = wave * 32;
  f4v acc[2][8];
#pragma unroll
  for (int rt = 0; rt < 2; ++rt)
#pragma unroll
    for (int ct = 0; ct < 8; ++ct) acc[rt][ct] = {0.f, 0.f, 0.f, 0.f};
  s8v a[2][4];
#pragma unroll
  for (int rt = 0; rt < 2; ++rt)
#pragma unroll
    for (int kq = 0; kq < 4; ++kq)
      a[rt][kq] = *(const s8v*)&Ab[(wr + rt * 16 + l15) * 132 + kq * 32 + quad * 8];
#pragma unroll
  for (int ct = 0; ct < 8; ++ct) {
    s8v b[4];
#pragma unroll
    for (int kq = 0; kq < 4; ++kq)
      b[kq] = *(const s8v*)&Bb[(ct * 16 + l15) * 132 + kq * 32 + quad * 8];
#pragma unroll
    for (int rt = 0; rt < 2; ++rt)
#pragma unroll
      for (int kq = 0; kq < 4; ++kq)
        acc[rt][ct] = __builtin_amdgcn_mfma_f32_16x16x32_bf16(a[rt][kq], b[kq], acc[rt][ct], 0, 0, 0);
  }
  __syncthreads();
  // stage adjacency bit tiles (both orientations) into LDS (reuse Ab)
  uint32_t* bl = (uint32_t*)Ab;   // bl[lr*4+w]: bits(row=rbase+lr, cols cbase..+127)
  uint32_t* blT = bl + 512;       // blT[lc*4+w]: bits(row=cbase+lc, cols rbase..+127)
#pragma unroll
  for (int it = 0; it < 2; ++it) {
    int idx = tid + it * 256;
    int r = idx >> 2, wq = idx & 3;
    bl[idx] = bits[(rbase + r) * 256 + (cbase >> 5) + wq];
    blT[idx] = bits[(cbase + r) * 256 + (rbase >> 5) + wq];
  }
  __syncthreads();
  float lsum = 0.f, lsq = 0.f, les = 0.f;
  float lmin = 3.4e38f, lmax = -3.4e38f;
  bool diag = (bx == by);
#pragma unroll
  for (int rt = 0; rt < 2; ++rt)
#pragma unroll
    for (int ct = 0; ct < 8; ++ct)
#pragma unroll
      for (int reg = 0; reg < 4; ++reg) {
        int lr = wr + rt * 16 + quad * 4 + reg;
        int lc = ct * 16 + l15;
        if (diag && lc < lr) continue;          // upper triangle incl. diagonal
        float v = acc[rt][ct][reg];
        bool ondiag = diag && (lc == lr);
        float wgt = ondiag ? 1.f : 2.f;
        lsum += wgt * v;
        lsq += wgt * v * v;
        lmin = fminf(lmin, v);
        lmax = fmaxf(lmax, v);
        unsigned eb = (bl[lr * 4 + (lc >> 5)] >> (lc & 31)) & 1u;
        if (!ondiag) eb += (blT[lc * 4 + (lr >> 5)] >> (lr & 31)) & 1u;
        if (eb) les += (float)eb * v;
      }
  double dsum = (double)lsum, dsq = (double)lsq, des = (double)les;
#pragma unroll
  for (int o = 32; o > 0; o >>= 1) {
    dsum += __shfl_xor(dsum, o);
    dsq += __shfl_xor(dsq, o);
    des += __shfl_xor(des, o);
    lmin = fminf(lmin, __shfl_xor(lmin, o));
    lmax = fmaxf(lmax, __shfl_xor(lmax, o));
  }
  // cross-wave via LDS (Bb is dead after the MFMA loop + both barriers passed)
  double* shd = (double*)Bb;            // 4 waves x 3 doubles
  float* shf = (float*)(shd + 12);      // 4 waves x 2 floats
  if (lane == 0) {
    shd[wave * 3 + 0] = dsum; shd[wave * 3 + 1] = dsq; shd[wave * 3 + 2] = des;
    shf[wave * 2 + 0] = lmin; shf[wave * 2 + 1] = lmax;
  }
  __syncthreads();
  if (tid == 0) {
    double s = 0.0, q = 0.0, e = 0.0;
    float m0 = 3.4e38f, m1 = -3.4e38f;
#pragma unroll
    for (int w0 = 0; w0 < 4; ++w0) {
      s += shd[w0 * 3 + 0]; q += shd[w0 * 3 + 1]; e += shd[w0 * 3 + 2];
      m0 = fminf(m0, shf[w0 * 2 + 0]); m1 = fmaxf(m1, shf[w0 * 2 + 1]);
    }
    p_sum[pid] = s; p_sq[pid] = q; p_es[pid] = e;
    p_mn[pid] = m0; p_mx[pid] = m1;
  }
}

// gather chosen codes -> quantized output; per-block commit-loss partial (no fp atomics)
__global__ __launch_bounds__(128) void k_q(const unsigned long long* __restrict__ amax,
    const float* __restrict__ cnws, const float* __restrict__ h1, float* __restrict__ qout,
    float* __restrict__ pq) {
  int row = blockIdx.x, t = threadIdx.x;
  unsigned long long key = amax[row];
  int col = (int)(0xFFFFFFFFu - (uint32_t)(key & 0xFFFFFFFFull));
  float q = cnws[col * 128 + t];
  qout[row * 128 + t] = q;
  float dd = q - h1[row * 128 + t];
  float ss = dd * dd;
#pragma unroll
  for (int o = 32; o > 0; o >>= 1) ss += __shfl_xor(ss, o);
  __shared__ float p[2];
  if ((t & 63) == 0) p[t >> 6] = ss;
  __syncthreads();
  if (t == 0) pq[row] = p[0] + p[1];
}

// sum of squared diff (h1 - quantized_node) -> per-block partial
__global__ __launch_bounds__(256) void k_sqdiff(const float4* __restrict__ a, const float4* __restrict__ b,
                                                float* __restrict__ ps) {
  int i = blockIdx.x * 256 + threadIdx.x;
  float s = 0.f;
  const int total = N * 32;
  for (; i < total; i += gridDim.x * 256) {
    float4 x = a[i], y = b[i];
    float d0 = x.x - y.x, d1 = x.y - y.y, d2 = x.z - y.z, d3 = x.w - y.w;
    s += d0 * d0 + d1 * d1 + d2 * d2 + d3 * d3;
  }
#pragma unroll
  for (int o = 32; o > 0; o >>= 1) s += __shfl_xor(s, o);
  __shared__ float p[4];
  if ((threadIdx.x & 63) == 0) p[threadIdx.x >> 6] = s;
  __syncthreads();
  if (threadIdx.x == 0) ps[blockIdx.x] = p[0] + p[1] + p[2] + p[3];
}

// final reduction of all partials + loss assembly (single block)
__global__ __launch_bounds__(1024) void k_finish(const double* __restrict__ p_sum,
    const double* __restrict__ p_sq, const double* __restrict__ p_es,
    const float* __restrict__ p_mn, const float* __restrict__ p_mx,
    const float* __restrict__ pq, const float* __restrict__ ps,
    const uint32_t* __restrict__ scal_u, float* __restrict__ o_loss) {
  int tid = threadIdx.x;
  double sum = 0.0, sq = 0.0, es = 0.0, commit = 0.0, frec = 0.0;
  float mn = 3.4e38f, mx = -3.4e38f;
  for (int i = tid; i < 4096; i += 1024) {
    sum += p_sum[i]; sq += p_sq[i]; es += p_es[i];
    mn = fminf(mn, p_mn[i]); mx = fmaxf(mx, p_mx[i]);
  }
  for (int i = tid; i < 8192; i += 1024) commit += (double)pq[i];
  if (tid < 512) frec = (double)ps[tid];
#pragma unroll
  for (int o = 32; o > 0; o >>= 1) {
    sum += __shfl_xor(sum, o); sq += __shfl_xor(sq, o); es += __shfl_xor(es, o);
    commit += __shfl_xor(commit, o); frec += __shfl_xor(frec, o);
    mn = fminf(mn, __shfl_xor(mn, o)); mx = fmaxf(mx, __shfl_xor(mx, o));
  }
  __shared__ double shd[16][5];
  __shared__ float shf[16][2];
  int wave = tid >> 6, lane = tid & 63;
  if (lane == 0) {
    shd[wave][0] = sum; shd[wave][1] = sq; shd[wave][2] = es;
    shd[wave][3] = commit; shd[wave][4] = frec;
    shf[wave][0] = mn; shf[wave][1] = mx;
  }
  __syncthreads();
  if (tid == 0) {
    double s = 0, q = 0, e = 0, c = 0, f = 0;
    float m0 = 3.4e38f, m1 = -3.4e38f;
    for (int w0 = 0; w0 < 16; ++w0) {
      s += shd[w0][0]; q += shd[w0][1]; e += shd[w0][2]; c += shd[w0][3]; f += shd[w0][4];
      m0 = fminf(m0, shf[w0][0]); m1 = fmaxf(m1, shf[w0][1]);
    }
    double mnd = (double)m0, mxd = (double)m1, U = (double)scal_u[2];
    const double N2 = 67108864.0;  // 8192^2
    double scl = 1.0 / (mxd - mnd);
    // sum over all (i,j) of (adj - (aq-mn)*scl)^2, adj=1 on U unique edge slots
    double mean = (scl * scl * (q - 2.0 * mnd * s + mnd * mnd * N2) - 2.0 * scl * (e - mnd * U) + U) / N2;
    *o_loss = (float)(f / 1048576.0 + sqrt(mean) + 0.25 * c / 1048576.0);
  }
}

extern "C" void kernel_launch(void* const* d_in, const int* in_sizes, int n_in,
                              void* d_out, int out_size, void* d_ws, size_t ws_size,
                              hipStream_t stream) {
  (void)in_sizes; (void)n_in; (void)out_size;
  const float* feats = (const float*)d_in[0];
  const int* src = (const int*)d_in[1];
  const int* dst = (const int*)d_in[2];
  const float* W1 = (const float*)d_in[3];
  const float* b1 = (const float*)d_in[4];
  const float* W2 = (const float*)d_in[5];
  const float* b2 = (const float*)d_in[6];
  const float* dec1W = (const float*)d_in[7];
  const float* dec1b = (const float*)d_in[8];
  const float* dec2W = (const float*)d_in[9];
  const float* dec2b = (const float*)d_in[10];
  const float* linW = (const float*)d_in[11];
  const float* linb = (const float*)d_in[12];
  const float* codebook = (const float*)d_in[13];

  float* out = (float*)d_out;
  float* o_h1 = out;                    // [N,128]
  float* o_q = out + 1048576;           // [N,128]
  float* o_h3 = out + 2097152;          // [N,128]
  float* o_out = out + 3145728;         // [N,64]
  float* o_loss = out + 3670016;        // scalar
  float* o_dist = out + 3670017;        // [N,4096] (float-misaligned base!)
  float* o_cn = out + 37224449;         // [C,128]  (float-misaligned base!)

  char* w = (char*)d_ws;
  size_t off = 0;
  auto alloc = [&](size_t b) { char* p = w + off; off = (off + b + 255) & ~(size_t)255; return p; };
  uint32_t* bits = (uint32_t*)alloc(8388608);            // N*N/8 adjacency bitmask
  int* dego = (int*)alloc(N * 4);
  int* degi = (int*)alloc(N * 4);
  unsigned long long* amax = (unsigned long long*)alloc(N * 8);
  uint32_t* scal_u = (uint32_t*)alloc(256);              // [2]=U unique-edge count
  size_t zero_bytes = off;                               // everything above must start at 0
  int* rowptr = (int*)alloc((N + 1) * 4);
  int* cursor = (int*)alloc(N * 4);
  int* csr = (int*)alloc(E * 4);
  float* nsrc = (float*)alloc(N * 4);
  float* ndst = (float*)alloc(N * 4);
  float* tmp = (float*)alloc((size_t)N * D * 4);
  float* agg = (float*)alloc((size_t)N * D * 4);
  float* xn = (float*)alloc((size_t)N * D * 4);
  float* cnws = (float*)alloc((size_t)C * D * 4);        // aligned copy of cn
  float* qe = (float*)alloc((size_t)N * D * 4);
  float* qn = (float*)alloc((size_t)N * D * 4);
  double* p_sum = (double*)alloc(4096 * 8);              // adjq per-block partials (fully written)
  double* p_sq = (double*)alloc(4096 * 8);
  double* p_es = (double*)alloc(4096 * 8);
  float* p_mn = (float*)alloc(4096 * 4);
  float* p_mx = (float*)alloc(4096 * 4);
  float* pq = (float*)alloc(8192 * 4);                   // commit partials
  float* ps = (float*)alloc(512 * 4);                    // frec partials
  // qb (bf16 copy of qe) aliases tmp: tmp's live ranges are conv1 (before) and conv2
  // (after k_adjq) — stream order makes the overlap safe, saves 2 MB of ws.
  unsigned short* qb = (unsigned short*)tmp;
  if (ws_size < off) return;  // insufficient scratch (will fail validation loudly)

  hipMemsetAsync(d_ws, 0, zero_bytes, stream);

  // graph structure
  k_degree<<<E / 256, 256, 0, stream>>>(src, dst, bits, dego, degi, scal_u);
  k_norms<<<N / 256, 256, 0, stream>>>(dego, degi, nsrc, ndst);
  k_scan<<<1, 1024, 0, stream>>>(degi, rowptr, cursor);
  k_scatter<<<E / 256, 256, 0, stream>>>(src, dst, cursor, csr);

  // conv1: h1 = relu((scatter(feats*nsrc)*ndst) @ W1 + b1)
  k_scale<<<N * 32 / 256, 256, 0, stream>>>((const float4*)feats, nsrc, (float4*)tmp);
  k_aggregate<<<N, 128, 0, stream>>>(rowptr, csr, tmp, ndst, agg);
  k_mm<128, true><<<N / 32, 256, 0, stream>>>(agg, W1, b1, o_h1);

  // VQ: cn, xn, dist (+argmax), q, commit loss partials
  k_l2norm<<<C / 4, 256, 0, stream>>>(codebook, cnws, o_cn, C);
  k_l2norm<<<N / 4, 256, 0, stream>>>(o_h1, xn, nullptr, N);
  k_gemm<<<dim3(C / 128, N / 128), 256, 0, stream>>>(xn, cnws, o_dist, amax);
  k_q<<<N, 128, 0, stream>>>(amax, cnws, o_h1, o_q, pq);

  // decoders
  k_mm<128, false><<<N / 32, 256, 0, stream>>>(o_q, dec1W, dec1b, qe);
  k_mm<128, false><<<N / 32, 256, 0, stream>>>(o_q, dec2W, dec2b, qn);
  k_sqdiff<<<512, 256, 0, stream>>>((const float4*)o_h1, (const float4*)qn, ps);

  // adjacency reconstruction loss: bf16 MFMA over upper-triangle blocks, per-block partials
  k_tobf16<<<N * 32 / 256, 256, 0, stream>>>((const float4*)qe, (ushort4*)qb);
  k_adjq<<<dim3(N / 128, N / 128), 256, 0, stream>>>(qb, bits, p_sum, p_sq, p_es, p_mn, p_mx);

  // conv2 on quantized_edge + linear head
  k_scale<<<N * 32 / 256, 256, 0, stream>>>((const float4*)qe, nsrc, (float4*)tmp);
  k_aggregate<<<N, 128, 0, stream>>>(rowptr, csr, tmp, ndst, agg);
  k_mm<128, true><<<N / 32, 256, 0, stream>>>(agg, W2, b2, o_h3);
  k_mm<64, false><<<N / 64, 256, 0, stream>>>(o_h3, linW, linb, o_out);

  k_finish<<<1, 1024, 0, stream>>>(p_sum, p_sq, p_es, p_mn, p_mx, pq, ps, scal_u, o_loss);
}